// Round 6
// baseline (609.753 us; speedup 1.0000x reference)
//
#include <hip/hip_runtime.h>

typedef unsigned short u16;
typedef unsigned int   u32;
typedef __attribute__((ext_vector_type(8))) short bf16x8;
typedef __attribute__((ext_vector_type(4))) float f32x4;

#define MFMA_BF16 __builtin_amdgcn_mfma_f32_16x16x32_bf16
#define LOG2E 1.4426950408889634f

__device__ __forceinline__ u16 f2bf(float f) {
    u32 x = __builtin_bit_cast(u32, f);
    u32 r = (x + 0x7fffu + ((x >> 16) & 1u)) >> 16;
    return (u16)r;
}
// one-instruction pack: dst.lo = bf16(lo), dst.hi = bf16(hi)  (RNE)
__device__ __forceinline__ u32 cvt_pk_bf16(float lo, float hi) {
    u32 r;
    asm("v_cvt_pk_bf16_f32 %0, %1, %2" : "=v"(r) : "v"(lo), "v"(hi));
    return r;
}
__device__ __forceinline__ float exp2_asm(float x) {
    float r;
    asm("v_exp_f32 %0, %1" : "=v"(r) : "v"(x));
    return r;
}
__device__ __forceinline__ float rcp_asm(float x) {
    float r;
    asm("v_rcp_f32 %0, %1" : "=v"(r) : "v"(x));
    return r;
}
// mish(x) = x * (p^2-1)/(p^2+1), p = 1+e^x. Written as x*(1 - 2/(p^2+1)):
// graceful at both infinities (e=0 -> r=0; e=inf -> r=1), no cmp/sel, no div.
__device__ __forceinline__ float mishf(float x) {
    float e = exp2_asm(x * LOG2E);
    float p = 1.f + e;
    float d = __builtin_fmaf(p, p, 1.f);
    float r = __builtin_fmaf(-2.f, rcp_asm(d), 1.f);
    return x * r;
}

// ---------------------------------------------------------------------------
// MFMA GEMM: C[M,N] = bf16( A[M,K] @ W[K,N] * scale ), fp32 in, bf16 out.
// Tile 128M x 64N, K-step 32, 256 thr. M % 128 == 0, N = 1024, K = 256.
// ---------------------------------------------------------------------------
__global__ __launch_bounds__(256) void gemm_mfma(
    const float* __restrict__ A, const float* __restrict__ W, u16* __restrict__ C,
    int M, int N, int K, float scale)
{
    __shared__ u16 As[128 * 40];
    __shared__ u16 Bf[4 * 64 * 8];

    const int tid = threadIdx.x;
    const int lane = tid & 63, wv = tid >> 6;
    const int qd = lane >> 4, ln = lane & 15;
    const int m0 = blockIdx.y * 128, n0 = blockIdx.x * 64;

    f32x4 acc[2][4];
#pragma unroll
    for (int a = 0; a < 2; ++a)
#pragma unroll
        for (int nt = 0; nt < 4; ++nt) acc[a][nt] = (f32x4){0.f, 0.f, 0.f, 0.f};

    for (int k0 = 0; k0 < K; k0 += 32) {
        {
            int r = tid >> 1, kh = (tid & 1) * 16;
            const float* ap = A + (size_t)(m0 + r) * K + k0 + kh;
            float4 a0 = ((const float4*)ap)[0];
            float4 a1 = ((const float4*)ap)[1];
            float4 a2 = ((const float4*)ap)[2];
            float4 a3 = ((const float4*)ap)[3];
            uint4 p0, p1;
            p0.x = cvt_pk_bf16(a0.x, a0.y);
            p0.y = cvt_pk_bf16(a0.z, a0.w);
            p0.z = cvt_pk_bf16(a1.x, a1.y);
            p0.w = cvt_pk_bf16(a1.z, a1.w);
            p1.x = cvt_pk_bf16(a2.x, a2.y);
            p1.y = cvt_pk_bf16(a2.z, a2.w);
            p1.z = cvt_pk_bf16(a3.x, a3.y);
            p1.w = cvt_pk_bf16(a3.z, a3.w);
            *(uint4*)&As[r * 40 + kh]     = p0;
            *(uint4*)&As[r * 40 + kh + 8] = p1;
        }
        {
            int nt = tid >> 6, q = (tid >> 4) & 3, nn = tid & 15;
            const float* wp = W + (size_t)(k0 + q * 8) * N + n0 + nt * 16 + nn;
            float w0 = wp[0], w1 = wp[(size_t)1 * N], w2 = wp[(size_t)2 * N], w3 = wp[(size_t)3 * N];
            float w4 = wp[(size_t)4 * N], w5 = wp[(size_t)5 * N], w6 = wp[(size_t)6 * N], w7 = wp[(size_t)7 * N];
            uint4 u;
            u.x = cvt_pk_bf16(w0, w1);
            u.y = cvt_pk_bf16(w2, w3);
            u.z = cvt_pk_bf16(w4, w5);
            u.w = cvt_pk_bf16(w6, w7);
            *(uint4*)&Bf[tid * 8] = u;
        }
        __syncthreads();
        bf16x8 af0 = *(const bf16x8*)&As[(wv * 32 + ln) * 40 + qd * 8];
        bf16x8 af1 = *(const bf16x8*)&As[(wv * 32 + 16 + ln) * 40 + qd * 8];
#pragma unroll
        for (int nt = 0; nt < 4; ++nt) {
            bf16x8 bfr = *(const bf16x8*)&Bf[(nt * 64 + lane) * 8];
            acc[0][nt] = MFMA_BF16(af0, bfr, acc[0][nt], 0, 0, 0);
            acc[1][nt] = MFMA_BF16(af1, bfr, acc[1][nt], 0, 0, 0);
        }
        __syncthreads();
    }
#pragma unroll
    for (int a = 0; a < 2; ++a)
#pragma unroll
        for (int nt = 0; nt < 4; ++nt) {
            u32 pk0 = cvt_pk_bf16(acc[a][nt][0] * scale, acc[a][nt][1] * scale);
            u32 pk1 = cvt_pk_bf16(acc[a][nt][2] * scale, acc[a][nt][3] * scale);
            size_t base = (size_t)(m0 + wv * 32 + a * 16 + qd * 4) * N + n0 + nt * 16 + ln;
            C[base]               = (u16)pk0;
            C[base + (size_t)N]   = (u16)(pk0 >> 16);
            C[base + (size_t)2*N] = (u16)pk1;
            C[base + (size_t)3*N] = (u16)(pk1 >> 16);
        }
}

// ---------------------------------------------------------------------------
// transpose cv[b*512+j][1024 ch] -> cvT[(b*1024+ch)*512 + j]. 64x64 tiles.
// ---------------------------------------------------------------------------
__global__ __launch_bounds__(256) void transpose_cv(
    const u16* __restrict__ cv, u16* __restrict__ cvT)
{
    __shared__ u16 T[64 * 80];
    const int tid = threadIdx.x;
    const int ct = blockIdx.x * 64, jt = blockIdx.y * 64, b = blockIdx.z;
    {
        int j_l = tid >> 2, seg = tid & 3;
        const u16* src = cv + (size_t)(b * 512 + jt + j_l) * 1024 + ct + seg * 16;
        uint4 v0 = ((const uint4*)src)[0];
        uint4 v1 = ((const uint4*)src)[1];
        u16* tp = &T[seg * 16 * 80 + j_l];
        tp[0*80] = (u16)(v0.x & 0xffff); tp[1*80] = (u16)(v0.x >> 16);
        tp[2*80] = (u16)(v0.y & 0xffff); tp[3*80] = (u16)(v0.y >> 16);
        tp[4*80] = (u16)(v0.z & 0xffff); tp[5*80] = (u16)(v0.z >> 16);
        tp[6*80] = (u16)(v0.w & 0xffff); tp[7*80] = (u16)(v0.w >> 16);
        tp[8*80] = (u16)(v1.x & 0xffff); tp[9*80] = (u16)(v1.x >> 16);
        tp[10*80] = (u16)(v1.y & 0xffff); tp[11*80] = (u16)(v1.y >> 16);
        tp[12*80] = (u16)(v1.z & 0xffff); tp[13*80] = (u16)(v1.z >> 16);
        tp[14*80] = (u16)(v1.w & 0xffff); tp[15*80] = (u16)(v1.w >> 16);
    }
    __syncthreads();
    {
        int ch_l = tid >> 2, sg = tid & 3;
        u16* dst = cvT + (size_t)(b * 1024 + ct + ch_l) * 512 + jt + sg * 16;
        ((uint4*)dst)[0] = *(const uint4*)&T[ch_l * 80 + sg * 16];
        ((uint4*)dst)[1] = *(const uint4*)&T[ch_l * 80 + sg * 16 + 8];
    }
}

// ---------------------------------------------------------------------------
// Prep: WoT[col][k] bf16; W1/W2 swizzled to MFMA B-frag order.
// W2 additionally: (a) K-slot permuted to match attn's packed-mish mt layout
//     (slot p holds hidden ch (p&1)*16 + (p>>1)), and (b) pre-scaled by
//     log2(e) so the softmax exp becomes a bare v_exp_f32 (exp2).
// ---------------------------------------------------------------------------
__global__ __launch_bounds__(256) void prep(
    const float* __restrict__ Wo, const float* __restrict__ W1, const float* __restrict__ W2,
    u16* __restrict__ WoT, u16* __restrict__ w1b, u16* __restrict__ w2b)
{
    const int bb = blockIdx.x, t = threadIdx.x;
    if (bb < 256) {
#pragma unroll
        for (int kk = 0; kk < 4; ++kk)
            WoT[(size_t)t * 1024 + bb * 4 + kk] = f2bf(Wo[(size_t)(bb * 4 + kk) * 256 + t]);
    } else {
        for (int u = 0; u < 32; ++u) {        // W1: frag f = ks*8+nt
            int idx = t + 256 * u;
            int j = idx & 7, lane = (idx >> 3) & 63, f = idx >> 9;
            int n = lane & 15, q = lane >> 4, ntc = f & 7, ks = f >> 3;
            w1b[idx] = f2bf(W1[(ks * 32 + q * 8 + j) * 128 + ntc * 16 + n]);
        }
        for (int u = 0; u < 32; ++u) {        // W2: frag f = ks*4+ot, K-permuted + log2e
            int idx = t + 256 * u;
            int j = idx & 7, lane = (idx >> 3) & 63, f = idx >> 9;
            int n = lane & 15, q = lane >> 4, ot = f & 3, ks = f >> 2;
            int k = q * 8 + j;
            int ch = ((k & 1) << 4) | (k >> 1);
            w2b[idx] = f2bf(W2[(ks * 32 + ch) * 64 + ot * 16 + n] * LOG2E);
        }
    }
}

// ---------------------------------------------------------------------------
// attn9: R5 occupancy design with the LDS-layout bug fixed.
// R5 NaN root cause: W1B needs 16384 B (16 frags x 64 lanes x 8 bf16; the
// staging loop copies 4096 u32) but every layout since R0 reserved only
// 8192 B. At 1 blk/CU the overrun landed in unoccupied LDS slack (R0/R1/R4
// passed); R5 placed DNL/DDL exactly there -> W1 frag reads returned
// accumulated exps -> exp2(garbage) -> inf/inf -> NaN.
// Fix: full 16 KB W1B; drop MT cg-parity dbuf (10240->5120 B, TLP at 2
// waves/SIMD hides the WAR it addressed). Layout now 81408 B/block;
// x2 blocks = 162816 <= 163840 -> 2 blocks/CU co-resident.
// Register plan unchanged from R5: no prefetch arrays, no persistent qkf,
// dn/dd -> LDS atomics, per-ot exp temps, 2 barriers/pass, bounds (256,2).
// ---------------------------------------------------------------------------
__global__ __launch_bounds__(256, 2) void attn5(
    const u16* __restrict__ qk,      // [2048][1024] bf16 (scale folded)
    const u16* __restrict__ cqk,     // [8192][1024] bf16
    const u16* __restrict__ cvT,     // [16][1024][512] bf16
    const float* __restrict__ bde,   // [16][512][128][32]
    const float* __restrict__ bdis,  // [16][512][128][3]
    const u16* __restrict__ w1b, const u16* __restrict__ w2b,
    const float* __restrict__ b2,
    float* __restrict__ partial)
{
    __shared__ __align__(16) char smem[81408];
    u16*   ES  = (u16*)smem;             // 20480 B: [256 rows=(i*16+j)][40]
    u16*   MT  = (u16*)(smem + 20480);   //  5120 B: per-wave miniT [4][16][40]
    float* BD  = (float*)(smem + 25600); //  4096 B: bdis stage [16 i][16 j][4]
    u16*   EST = (u16*)(smem + 29696);   // 25088 B: Estage [32 h][16 i][24+pad]
    u16*   W1B = (u16*)(smem + 54784);   // 16384 B: W1 frags (FULL size now)
    float* DNL = (float*)(smem + 71168); //  4096 B: denom acc [16 i][4 ot][16 ln]
    float* DDL = (float*)(smem + 75264); //  6144 B: dis acc [16 i][3 d][2 o][16 ln]

    const int tid = threadIdx.x;
    const int lane = tid & 63, wv = tid >> 6;
    const int qd = lane >> 4, ln = lane & 15;
    const int nblk = blockIdx.x;
    const int xcd = nblk & 7, g = nblk >> 3;
    const int b = xcd * 2 + (g & 1);
    const int r2 = g >> 1;
    const int it = r2 >> 2, jq = r2 & 3;
    const int i0 = it * 16;
    const int pidx = (b * 8 + it) * 4 + jq;

    for (int k = tid; k < 4096; k += 256) ((u32*)W1B)[k] = ((const u32*)w1b)[k];
    for (int k = tid; k < 1024; k += 256) DNL[k] = 0.f;
    for (int k = tid; k < 1536; k += 256) DDL[k] = 0.f;

    float b2r[4];
#pragma unroll
    for (int ot = 0; ot < 4; ++ot) b2r[ot] = b2[ot * 16 + ln] * LOG2E;

    const u16* qrow = qk + ((size_t)(b * 128 + i0 + ln)) * 1024 + qd * 8;
    const int ii = tid & 15, jj = tid >> 4;   // bdis stage mapping

    f32x4 oacc[8][2];
#pragma unroll
    for (int a = 0; a < 8; ++a)
#pragma unroll
        for (int c = 0; c < 2; ++c) oacc[a][c] = (f32x4){0.f, 0.f, 0.f, 0.f};

    __syncthreads();

#pragma clang loop unroll(disable)
    for (int ps = 0; ps < 8; ++ps) {
        const int jg0 = jq * 128 + ps * 16;

        // ---- P1: sim (MFMA) -> ES; stage bdis -> BD ----
        {
            const u16* crow = cqk + (size_t)(b * 512 + jg0 + ln) * 1024 + qd * 8;
#pragma unroll
            for (int hh = 0; hh < 4; ++hh) {
                const int h0 = wv * 8 + hh * 2;
                bf16x8 a0 = *(const bf16x8*)(qrow + h0 * 32);
                bf16x8 a1 = *(const bf16x8*)(qrow + (h0 + 1) * 32);
                bf16x8 b0 = *(const bf16x8*)(crow + h0 * 32);
                bf16x8 b1 = *(const bf16x8*)(crow + (h0 + 1) * 32);
                f32x4 c0 = (f32x4){0.f, 0.f, 0.f, 0.f}, c1 = c0;
                c0 = MFMA_BF16(a0, b0, c0, 0, 0, 0);
                c1 = MFMA_BF16(a1, b1, c1, 0, 0, 0);
#pragma unroll
                for (int r = 0; r < 4; ++r)
                    *(u32*)&ES[((qd * 4 + r) * 16 + ln) * 40 + h0] = cvt_pk_bf16(c0[r], c1[r]);
            }
            const float* sp = bdis + ((size_t)(b * 512 + jg0 + jj) * 128 + i0 + ii) * 3;
            float* dp2 = &BD[(ii * 16 + jj) * 4];
            dp2[0] = sp[0]; dp2[1] = sp[1]; dp2[2] = sp[2];
        }
        __syncthreads();   // P1-end

        // ---- P2: per s (i = wv*4+s): MLP1 -> mish -> MLP2 -> exp2 ----
#pragma unroll
        for (int s = 0; s < 4; ++s) {
            const int i_loc = wv * 4 + s;
            bf16x8 af0 = *(const bf16x8*)&ES[(i_loc * 16 + ln) * 40 + qd * 8];
            bf16x8 af1;
            {   // bde channels ARE the A-frag: direct global load + pk-convert
                const float* dp = bde + (((size_t)(b * 512 + jg0 + ln)) * 128 + i0 + i_loc) * 32 + qd * 8;
                float4 a0 = ((const float4*)dp)[0];
                float4 a1 = ((const float4*)dp)[1];
                uint4 u;
                u.x = cvt_pk_bf16(a0.x, a0.y);
                u.y = cvt_pk_bf16(a0.z, a0.w);
                u.z = cvt_pk_bf16(a1.x, a1.y);
                u.w = cvt_pk_bf16(a1.z, a1.w);
                af1 = __builtin_bit_cast(bf16x8, u);
            }
            f32x4 uacc[4];
#pragma unroll
            for (int ot = 0; ot < 4; ++ot) uacc[ot] = (f32x4){0.f, 0.f, 0.f, 0.f};
            u16* mtp = MT + wv * 640;
#pragma unroll
            for (int cg = 0; cg < 4; ++cg) {
                bf16x8 w00 = *(const bf16x8*)&W1B[((cg * 2 + 0) * 64 + lane) * 8];
                bf16x8 w01 = *(const bf16x8*)&W1B[((cg * 2 + 1) * 64 + lane) * 8];
                bf16x8 w10 = *(const bf16x8*)&W1B[((8 + cg * 2 + 0) * 64 + lane) * 8];
                bf16x8 w11 = *(const bf16x8*)&W1B[((8 + cg * 2 + 1) * 64 + lane) * 8];
                f32x4 t0 = (f32x4){0.f, 0.f, 0.f, 0.f}, t1 = t0;
                t0 = MFMA_BF16(af0, w00, t0, 0, 0, 0);
                t0 = MFMA_BF16(af1, w10, t0, 0, 0, 0);
                t1 = MFMA_BF16(af0, w01, t1, 0, 0, 0);
                t1 = MFMA_BF16(af1, w11, t1, 0, 0, 0);
                // packed mish pair -> one ds_write_b32; u16 slot 2m holds ch m,
                // slot 2m+1 holds ch 16+m (w2b K-order permuted to match)
#pragma unroll
                for (int r = 0; r < 4; ++r) {
                    u32 pk = cvt_pk_bf16(mishf(t0[r]), mishf(t1[r]));
                    *(u32*)&mtp[(qd * 4 + r) * 40 + (ln << 1)] = pk;
                }
                bf16x8 ta = *(const bf16x8*)&mtp[ln * 40 + qd * 8];
#pragma unroll
                for (int ot = 0; ot < 4; ++ot) {
                    bf16x8 wf = *(const bf16x8*)(w2b + ((size_t)(cg * 4 + ot) * 64 + lane) * 8);
                    uacc[ot] = MFMA_BF16(ta, wf, uacc[ot], 0, 0, 0);
                }
            }
            // per-ot: exp2 -> DNL atomic; ot<2 -> EST; ot>=2 -> DDL atomics
#pragma unroll
            for (int ot = 0; ot < 4; ++ot) {
                float e0 = exp2_asm(uacc[ot][0] + b2r[ot]);
                float e1 = exp2_asm(uacc[ot][1] + b2r[ot]);
                float e2 = exp2_asm(uacc[ot][2] + b2r[ot]);
                float e3 = exp2_asm(uacc[ot][3] + b2r[ot]);
                atomicAdd(&DNL[i_loc * 64 + ot * 16 + ln], (e0 + e1) + (e2 + e3));
                if (ot < 2) {
                    const int base = (ot * 16 + ln) * 392 + i_loc * 24 + qd * 4;
                    *(u32*)&EST[base]     = cvt_pk_bf16(e0, e1);
                    *(u32*)&EST[base + 2] = cvt_pk_bf16(e2, e3);
                } else {
                    const int o = ot - 2;
                    float ee[4] = {e0, e1, e2, e3};
                    float ax = 0.f, ay = 0.f, az = 0.f;
#pragma unroll
                    for (int r = 0; r < 4; ++r) {
                        float4 bp = *(const float4*)&BD[(i_loc * 16 + qd * 4 + r) * 4];
                        ax = __builtin_fmaf(ee[r], bp.x, ax);
                        ay = __builtin_fmaf(ee[r], bp.y, ay);
                        az = __builtin_fmaf(ee[r], bp.z, az);
                    }
                    atomicAdd(&DDL[i_loc * 96 +      o * 16 + ln], ax);
                    atomicAdd(&DDL[i_loc * 96 + 32 + o * 16 + ln], ay);
                    atomicAdd(&DDL[i_loc * 96 + 64 + o * 16 + ln], az);
                }
            }
        }
        __syncthreads();   // P2-end

        // ---- P3: PV via MFMA: A = Estage (K=16 zero-padded), B = cvT.
        //      No trailing barrier: EST rewrite happens in next pass P2,
        //      which all waves can only reach via next P1-end barrier. ----
#pragma unroll
        for (int hh = 0; hh < 8; ++hh) {
            const int h = wv * 8 + hh;
            bf16x8 af = (bf16x8){0, 0, 0, 0, 0, 0, 0, 0};
            if (qd < 2) af = *(const bf16x8*)&EST[h * 392 + ln * 24 + qd * 8];
#pragma unroll
            for (int nt = 0; nt < 2; ++nt) {
                bf16x8 bfr = (bf16x8){0, 0, 0, 0, 0, 0, 0, 0};
                if (qd < 2)
                    bfr = *(const bf16x8*)(cvT + ((size_t)(b * 1024 + h * 32 + nt * 16 + ln)) * 512 + jg0 + qd * 8);
                oacc[hh][nt] = MFMA_BF16(af, bfr, oacc[hh][nt], 0, 0, 0);
            }
        }
    }

    // ---- epilogue: write partials (DNL/DDL final as of last P2-end barrier) ----
    float* P = partial + (size_t)pidx * 18944;
#pragma unroll
    for (int hh = 0; hh < 8; ++hh)
#pragma unroll
        for (int nt = 0; nt < 2; ++nt)
#pragma unroll
            for (int r = 0; r < 4; ++r)
                P[(size_t)(qd * 4 + r) * 1024 + (wv * 8 + hh) * 32 + nt * 16 + ln] = oacc[hh][nt][r];
    for (int k = tid; k < 1024; k += 256) P[16384 + k] = DNL[k];
    for (int k = tid; k < 1536; k += 256) P[17408 + k] = DDL[k];
}

// ---------------------------------------------------------------------------
// finalize: per (b,it): combine 4 jq partials, normalize, Wo epilogue (MFMA),
// dis-MLP. 128 blocks x 256 threads.
// ---------------------------------------------------------------------------
__global__ __launch_bounds__(256, 2) void finalize(
    const float* __restrict__ partial, const u16* __restrict__ WoT,
    const float* __restrict__ bo,
    const float* __restrict__ Wd1, const float* __restrict__ bd1,
    const float* __restrict__ Wd2, const float* __restrict__ bd2,
    float* __restrict__ out0, float* __restrict__ out1)
{
    __shared__ float denomL[1024];
    __shared__ u16 preL[16 * 1032];
    __shared__ float odisL[1536];
    __shared__ float r1L[3072];

    const int tid = threadIdx.x;
    const int f = blockIdx.x;
    const int b = f >> 3, it = f & 7;
    const int row0 = b * 128 + it * 16;
    const float* P0 = partial + (size_t)(f * 4 + 0) * 18944;
    const float* P1 = partial + (size_t)(f * 4 + 1) * 18944;
    const float* P2 = partial + (size_t)(f * 4 + 2) * 18944;
    const float* P3 = partial + (size_t)(f * 4 + 3) * 18944;

    for (int k = tid; k < 1024; k += 256)
        denomL[k] = P0[16384 + k] + P1[16384 + k] + P2[16384 + k] + P3[16384 + k];
    __syncthreads();

    {
        const int h = tid >> 3;
#pragma unroll
        for (int i = 0; i < 16; ++i) {
            float4 a = *(const float4*)&P0[(size_t)i * 1024 + tid * 4];
            float4 bq = *(const float4*)&P1[(size_t)i * 1024 + tid * 4];
            float4 c = *(const float4*)&P2[(size_t)i * 1024 + tid * 4];
            float4 d = *(const float4*)&P3[(size_t)i * 1024 + tid * 4];
            float rdn = 1.f / denomL[i * 64 + h];
            u32 p0 = cvt_pk_bf16((a.x + bq.x + c.x + d.x) * rdn, (a.y + bq.y + c.y + d.y) * rdn);
            u32 p1 = cvt_pk_bf16((a.z + bq.z + c.z + d.z) * rdn, (a.w + bq.w + c.w + d.w) * rdn);
            *(uint2*)(void*)&preL[i * 1032 + tid * 4] = make_uint2(p0, p1);
        }
    }
    for (int idx = tid; idx < 1536; idx += 256) {
        int i = idx / 96, rm = idx % 96, h = rm & 31;
        odisL[idx] = (P0[17408 + idx] + P1[17408 + idx] + P2[17408 + idx] + P3[17408 + idx])
                     / denomL[i * 64 + 32 + h];
    }
    __syncthreads();

    {
        const int lane = tid & 63, wv = tid >> 6;
        const int qd = lane >> 4, ln = lane & 15;
        f32x4 acc[4];
#pragma unroll
        for (int nt = 0; nt < 4; ++nt) acc[nt] = (f32x4){0.f, 0.f, 0.f, 0.f};
#pragma clang loop unroll(disable)
        for (int ks = 0; ks < 32; ++ks) {
            bf16x8 af = *(const bf16x8*)&preL[ln * 1032 + ks * 32 + qd * 8];
#pragma unroll
            for (int nt = 0; nt < 4; ++nt) {
                bf16x8 wf = *(const bf16x8*)(WoT + ((size_t)(wv * 64 + nt * 16 + ln)) * 1024 + ks * 32 + qd * 8);
                acc[nt] = MFMA_BF16(af, wf, acc[nt], 0, 0, 0);
            }
        }
#pragma unroll
        for (int nt = 0; nt < 4; ++nt) {
            int col = wv * 64 + nt * 16 + ln;
            float bv = bo[col];
#pragma unroll
            for (int r = 0; r < 4; ++r)
                out0[(size_t)(row0 + qd * 4 + r) * 256 + col] = acc[nt][r] + bv;
        }
    }

    for (int idx = tid; idx < 3072; idx += 256) {
        int i = idx / 192, rm = idx % 192, d = rm / 64, c = rm & 63;
        float t = bd1[c];
#pragma unroll
        for (int hh = 0; hh < 32; ++hh)
            t += odisL[i * 96 + d * 32 + hh] * Wd1[hh * 64 + c];
        r1L[idx] = mishf(t);
    }
    __syncthreads();
    for (int idx = tid; idx < 1536; idx += 256) {
        int i = idx / 96, rm = idx % 96, d = rm >> 5, h = rm & 31;
        float v = bd2[h];
#pragma unroll
        for (int c = 0; c < 64; ++c)
            v += r1L[i * 192 + d * 64 + c] * Wd2[c * 32 + h];
        out1[(size_t)(row0 + i) * 96 + d * 32 + h] = v;
    }
}

extern "C" void kernel_launch(void* const* d_in, const int* in_sizes, int n_in,
                              void* d_out, int out_size, void* d_ws, size_t ws_size,
                              hipStream_t stream) {
    const float* x    = (const float*)d_in[0];
    const float* ctx  = (const float*)d_in[1];
    const float* bdis = (const float*)d_in[2];
    const float* bde  = (const float*)d_in[3];
    const float* Wqk  = (const float*)d_in[6];
    const float* Wcqk = (const float*)d_in[8];
    const float* Wcv  = (const float*)d_in[9];
    const float* Wm1  = (const float*)d_in[10];
    const float* Wm2  = (const float*)d_in[11];
    const float* bm2  = (const float*)d_in[12];
    const float* Wo   = (const float*)d_in[13];
    const float* bo   = (const float*)d_in[14];
    const float* Wd1  = (const float*)d_in[15];
    const float* bd1  = (const float*)d_in[16];
    const float* Wd2  = (const float*)d_in[17];
    const float* bd2  = (const float*)d_in[18];

    char* ws = (char*)d_ws;
    u16* qk_ws  = (u16*)(ws);                       // 4 MB
    u16* cqk_ws = (u16*)(ws + 4194304);             // 16 MB
    u16* cvT_ws = (u16*)(ws + 20971520);            // 16 MB
    u16* w1b    = (u16*)(ws + 37748736);            // 16 KB
    u16* w2b    = (u16*)(ws + 37765120);            // 16 KB
    u16* WoT    = (u16*)(ws + 37781504);            // 512 KB
    float* part = (float*)(ws + 38305792);          // 512*18944*4 = 38.8 MB
    u16* cv_rm  = (u16*)(ws + 38305792);            // 16 MB overlay (dead before part)

    float* out0 = (float*)d_out;
    float* out1 = out0 + (size_t)2048 * 256;

    const float SCALE = 0.17677669529663687f;       // 32^-0.5, folded into qk

    prep<<<257, 256, 0, stream>>>(Wo, Wm1, Wm2, WoT, w1b, w2b);
    gemm_mfma<<<dim3(16, 16), 256, 0, stream>>>(x,   Wqk,  qk_ws,  2048, 1024, 256, SCALE);
    gemm_mfma<<<dim3(16, 64), 256, 0, stream>>>(ctx, Wcqk, cqk_ws, 8192, 1024, 256, 1.0f);
    gemm_mfma<<<dim3(16, 64), 256, 0, stream>>>(ctx, Wcv,  cv_rm,  8192, 1024, 256, 1.0f);
    transpose_cv<<<dim3(16, 8, 16), 256, 0, stream>>>(cv_rm, cvT_ws);
    attn5<<<512, 256, 0, stream>>>(qk_ws, cqk_ws, cvT_ws, bde, bdis, w1b, w2b, bm2, part);
    finalize<<<128, 256, 0, stream>>>(part, WoT, bo, Wd1, bd1, Wd2, bd2, out0, out1);
}

// Round 7
// 537.548 us; speedup vs baseline: 1.1343x; 1.1343x over previous
//
#include <hip/hip_runtime.h>

typedef unsigned short u16;
typedef unsigned int   u32;
typedef __attribute__((ext_vector_type(8))) short bf16x8;
typedef __attribute__((ext_vector_type(4))) float f32x4;

#define MFMA_BF16 __builtin_amdgcn_mfma_f32_16x16x32_bf16
#define LOG2E 1.4426950408889634f

__device__ __forceinline__ u16 f2bf(float f) {
    u32 x = __builtin_bit_cast(u32, f);
    u32 r = (x + 0x7fffu + ((x >> 16) & 1u)) >> 16;
    return (u16)r;
}
// one-instruction pack: dst.lo = bf16(lo), dst.hi = bf16(hi)  (RNE)
__device__ __forceinline__ u32 cvt_pk_bf16(float lo, float hi) {
    u32 r;
    asm("v_cvt_pk_bf16_f32 %0, %1, %2" : "=v"(r) : "v"(lo), "v"(hi));
    return r;
}
__device__ __forceinline__ float exp2_asm(float x) {
    float r;
    asm("v_exp_f32 %0, %1" : "=v"(r) : "v"(x));
    return r;
}
__device__ __forceinline__ float rcp_asm(float x) {
    float r;
    asm("v_rcp_f32 %0, %1" : "=v"(r) : "v"(x));
    return r;
}
// mish(x) = x * (p^2-1)/(p^2+1), p = 1+e^x. Written as x*(1 - 2/(p^2+1)):
// graceful at both infinities (e=0 -> r=0; e=inf -> r=1), no cmp/sel, no div.
__device__ __forceinline__ float mishf(float x) {
    float e = exp2_asm(x * LOG2E);
    float p = 1.f + e;
    float d = __builtin_fmaf(p, p, 1.f);
    float r = __builtin_fmaf(-2.f, rcp_asm(d), 1.f);
    return x * r;
}

// ---------------------------------------------------------------------------
// MFMA GEMM: C[M,N] = bf16( A[M,K] @ W[K,N] * scale ), fp32 in, bf16 out.
// Tile 128M x 128N (R7: widened from 64N -- 16 MFMA per K-step against the
// same A-staging, halves staging cost per FLOP), K-step 32, 256 thr.
// ---------------------------------------------------------------------------
__global__ __launch_bounds__(256) void gemm_mfma(
    const float* __restrict__ A, const float* __restrict__ W, u16* __restrict__ C,
    int M, int N, int K, float scale)
{
    __shared__ u16 As[128 * 40];      // 10240 B
    __shared__ u16 Bf[8 * 64 * 8];    //  8192 B

    const int tid = threadIdx.x;
    const int lane = tid & 63, wv = tid >> 6;
    const int qd = lane >> 4, ln = lane & 15;
    const int m0 = blockIdx.y * 128, n0 = blockIdx.x * 128;

    f32x4 acc[2][8];
#pragma unroll
    for (int a = 0; a < 2; ++a)
#pragma unroll
        for (int nt = 0; nt < 8; ++nt) acc[a][nt] = (f32x4){0.f, 0.f, 0.f, 0.f};

    for (int k0 = 0; k0 < K; k0 += 32) {
        {
            int r = tid >> 1, kh = (tid & 1) * 16;
            const float* ap = A + (size_t)(m0 + r) * K + k0 + kh;
            float4 a0 = ((const float4*)ap)[0];
            float4 a1 = ((const float4*)ap)[1];
            float4 a2 = ((const float4*)ap)[2];
            float4 a3 = ((const float4*)ap)[3];
            uint4 p0, p1;
            p0.x = cvt_pk_bf16(a0.x, a0.y);
            p0.y = cvt_pk_bf16(a0.z, a0.w);
            p0.z = cvt_pk_bf16(a1.x, a1.y);
            p0.w = cvt_pk_bf16(a1.z, a1.w);
            p1.x = cvt_pk_bf16(a2.x, a2.y);
            p1.y = cvt_pk_bf16(a2.z, a2.w);
            p1.z = cvt_pk_bf16(a3.x, a3.y);
            p1.w = cvt_pk_bf16(a3.z, a3.w);
            *(uint4*)&As[r * 40 + kh]     = p0;
            *(uint4*)&As[r * 40 + kh + 8] = p1;
        }
        {
            int ntA = tid >> 6, q = (tid >> 4) & 3, nn = tid & 15;
#pragma unroll
            for (int h = 0; h < 2; ++h) {
                int nt = ntA + h * 4;
                const float* wp = W + (size_t)(k0 + q * 8) * N + n0 + nt * 16 + nn;
                float w0 = wp[0], w1 = wp[(size_t)1 * N], w2 = wp[(size_t)2 * N], w3 = wp[(size_t)3 * N];
                float w4 = wp[(size_t)4 * N], w5 = wp[(size_t)5 * N], w6 = wp[(size_t)6 * N], w7 = wp[(size_t)7 * N];
                uint4 u;
                u.x = cvt_pk_bf16(w0, w1);
                u.y = cvt_pk_bf16(w2, w3);
                u.z = cvt_pk_bf16(w4, w5);
                u.w = cvt_pk_bf16(w6, w7);
                *(uint4*)&Bf[(nt * 64 + q * 16 + nn) * 8] = u;
            }
        }
        __syncthreads();
        bf16x8 af0 = *(const bf16x8*)&As[(wv * 32 + ln) * 40 + qd * 8];
        bf16x8 af1 = *(const bf16x8*)&As[(wv * 32 + 16 + ln) * 40 + qd * 8];
#pragma unroll
        for (int nt = 0; nt < 8; ++nt) {
            bf16x8 bfr = *(const bf16x8*)&Bf[(nt * 64 + lane) * 8];
            acc[0][nt] = MFMA_BF16(af0, bfr, acc[0][nt], 0, 0, 0);
            acc[1][nt] = MFMA_BF16(af1, bfr, acc[1][nt], 0, 0, 0);
        }
        __syncthreads();
    }
#pragma unroll
    for (int a = 0; a < 2; ++a)
#pragma unroll
        for (int nt = 0; nt < 8; ++nt) {
            u32 pk0 = cvt_pk_bf16(acc[a][nt][0] * scale, acc[a][nt][1] * scale);
            u32 pk1 = cvt_pk_bf16(acc[a][nt][2] * scale, acc[a][nt][3] * scale);
            size_t base = (size_t)(m0 + wv * 32 + a * 16 + qd * 4) * N + n0 + nt * 16 + ln;
            C[base]               = (u16)pk0;
            C[base + (size_t)N]   = (u16)(pk0 >> 16);
            C[base + (size_t)2*N] = (u16)pk1;
            C[base + (size_t)3*N] = (u16)(pk1 >> 16);
        }
}

// ---------------------------------------------------------------------------
// transpose cv[b*512+j][1024 ch] -> cvT[(b*1024+ch)*512 + j]. 64x64 tiles.
// ---------------------------------------------------------------------------
__global__ __launch_bounds__(256) void transpose_cv(
    const u16* __restrict__ cv, u16* __restrict__ cvT)
{
    __shared__ u16 T[64 * 80];
    const int tid = threadIdx.x;
    const int ct = blockIdx.x * 64, jt = blockIdx.y * 64, b = blockIdx.z;
    {
        int j_l = tid >> 2, seg = tid & 3;
        const u16* src = cv + (size_t)(b * 512 + jt + j_l) * 1024 + ct + seg * 16;
        uint4 v0 = ((const uint4*)src)[0];
        uint4 v1 = ((const uint4*)src)[1];
        u16* tp = &T[seg * 16 * 80 + j_l];
        tp[0*80] = (u16)(v0.x & 0xffff); tp[1*80] = (u16)(v0.x >> 16);
        tp[2*80] = (u16)(v0.y & 0xffff); tp[3*80] = (u16)(v0.y >> 16);
        tp[4*80] = (u16)(v0.z & 0xffff); tp[5*80] = (u16)(v0.z >> 16);
        tp[6*80] = (u16)(v0.w & 0xffff); tp[7*80] = (u16)(v0.w >> 16);
        tp[8*80] = (u16)(v1.x & 0xffff); tp[9*80] = (u16)(v1.x >> 16);
        tp[10*80] = (u16)(v1.y & 0xffff); tp[11*80] = (u16)(v1.y >> 16);
        tp[12*80] = (u16)(v1.z & 0xffff); tp[13*80] = (u16)(v1.z >> 16);
        tp[14*80] = (u16)(v1.w & 0xffff); tp[15*80] = (u16)(v1.w >> 16);
    }
    __syncthreads();
    {
        int ch_l = tid >> 2, sg = tid & 3;
        u16* dst = cvT + (size_t)(b * 1024 + ct + ch_l) * 512 + jt + sg * 16;
        ((uint4*)dst)[0] = *(const uint4*)&T[ch_l * 80 + sg * 16];
        ((uint4*)dst)[1] = *(const uint4*)&T[ch_l * 80 + sg * 16 + 8];
    }
}

// ---------------------------------------------------------------------------
// Prep: WoT[col][k] bf16; W1/W2 swizzled to MFMA B-frag order.
// W2 additionally: (a) K-slot permuted to match attn's packed-mish mt layout
//     (slot p holds hidden ch (p&1)*16 + (p>>1)), and (b) pre-scaled by
//     log2(e) so the softmax exp becomes a bare v_exp_f32 (exp2).
// ---------------------------------------------------------------------------
__global__ __launch_bounds__(256) void prep(
    const float* __restrict__ Wo, const float* __restrict__ W1, const float* __restrict__ W2,
    u16* __restrict__ WoT, u16* __restrict__ w1b, u16* __restrict__ w2b)
{
    const int bb = blockIdx.x, t = threadIdx.x;
    if (bb < 256) {
#pragma unroll
        for (int kk = 0; kk < 4; ++kk)
            WoT[(size_t)t * 1024 + bb * 4 + kk] = f2bf(Wo[(size_t)(bb * 4 + kk) * 256 + t]);
    } else {
        for (int u = 0; u < 32; ++u) {        // W1: frag f = ks*8+nt
            int idx = t + 256 * u;
            int j = idx & 7, lane = (idx >> 3) & 63, f = idx >> 9;
            int n = lane & 15, q = lane >> 4, ntc = f & 7, ks = f >> 3;
            w1b[idx] = f2bf(W1[(ks * 32 + q * 8 + j) * 128 + ntc * 16 + n]);
        }
        for (int u = 0; u < 32; ++u) {        // W2: frag f = ks*4+ot, K-permuted + log2e
            int idx = t + 256 * u;
            int j = idx & 7, lane = (idx >> 3) & 63, f = idx >> 9;
            int n = lane & 15, q = lane >> 4, ot = f & 3, ks = f >> 2;
            int k = q * 8 + j;
            int ch = ((k & 1) << 4) | (k >> 1);
            w2b[idx] = f2bf(W2[(ks * 32 + ch) * 64 + ot * 16 + n] * LOG2E);
        }
    }
}

// ---------------------------------------------------------------------------
// attn10 = R4's attn7 (best verified: 266 us, register-rich prefetch at
// 1 wave/SIMD) with two fixes:
//  - W1B gets its true 16384 B (smem 76288; retires the latent overrun
//    that R5 exposed) -- layout audit, not behavior change at 1 blk/CU.
//  - P3-end barrier dropped (ES: cross-wave slices disjoint; EST P3-reads
//    precede each wave's arrival at next P1-end barrier, which precedes
//    next P2's EST writes; BD written in P3, read in next P2 across the
//    P1-end barrier). 3 -> 2 barriers/pass.
// R6 lesson locked in: occupancy>1 wave/SIMD is unreachable without losing
// more ILP than TLP repays (R2 spill, R6 starvation). Stay register-rich.
// ---------------------------------------------------------------------------
__global__ __launch_bounds__(256, 1) void attn5(
    const u16* __restrict__ qk,      // [2048][1024] bf16 (scale folded)
    const u16* __restrict__ cqk,     // [8192][1024] bf16
    const u16* __restrict__ cvT,     // [16][1024][512] bf16
    const float* __restrict__ bde,   // [16][512][128][32]
    const float* __restrict__ bdis,  // [16][512][128][3]
    const u16* __restrict__ w1b, const u16* __restrict__ w2b,
    const float* __restrict__ b2,
    float* __restrict__ partial)
{
    __shared__ __align__(16) char smem[76288];
    u16*   ES  = (u16*)smem;             // 20480 B: [256 rows=(i*16+j)][40]
    u16*   MT  = (u16*)(smem + 20480);   // 10240 B: per-wave miniT, cg-dbuf
    float* BD  = (float*)(smem + 30720); //  4096 B: bdis stage [16 i][16 j][4]
    u16*   EST = (u16*)(smem + 34816);   // 25088 B: Estage [32 h][16 i][24+pad]
    u16*   W1B = (u16*)(smem + 59904);   // 16384 B: W1 frags (full size)

    const int tid = threadIdx.x;
    const int lane = tid & 63, wv = tid >> 6;
    const int qd = lane >> 4, ln = lane & 15;
    const int nblk = blockIdx.x;
    const int xcd = nblk & 7, g = nblk >> 3;
    const int b = xcd * 2 + (g & 1);
    const int r2 = g >> 1;
    const int it = r2 >> 2, jq = r2 & 3;
    const int i0 = it * 16;
    const int pidx = (b * 8 + it) * 4 + jq;

    for (int k = tid; k < 4096; k += 256) ((u32*)W1B)[k] = ((const u32*)w1b)[k];

    float b2r[4];
#pragma unroll
    for (int ot = 0; ot < 4; ++ot) b2r[ot] = b2[ot * 16 + ln] * LOG2E;

    // qk A-frags: registers for the whole kernel (same i-tile every pass)
    bf16x8 qkf[8];
#pragma unroll
    for (int hh = 0; hh < 8; ++hh) {
        int h = wv * 8 + hh;
        qkf[hh] = *(const bf16x8*)(qk + ((size_t)(b * 128 + i0 + ln)) * 1024 + h * 32 + qd * 8);
    }

    const int ii = tid & 15, jj = tid >> 4;   // bdis stage mapping

    // ---- prologue: prefetch pass-0 inputs ----
    bf16x8 cqk_pf[8];
    float4 bde_pf[8];
    float bdp0, bdp1, bdp2;
    {
        const u16* crow = cqk + (size_t)(b * 512 + jq * 128 + ln) * 1024 + qd * 8;
#pragma unroll
        for (int hh = 0; hh < 8; ++hh)
            cqk_pf[hh] = *(const bf16x8*)(crow + (wv * 8 + hh) * 32);
#pragma unroll
        for (int s2 = 0; s2 < 4; ++s2) {
            const float* dps = bde + (((size_t)(b * 512 + jq * 128 + ln)) * 128 + i0 + wv * 4 + s2) * 32 + qd * 8;
            bde_pf[s2 * 2]     = ((const float4*)dps)[0];
            bde_pf[s2 * 2 + 1] = ((const float4*)dps)[1];
        }
        const float* sp = bdis + ((size_t)(b * 512 + jq * 128 + jj) * 128 + i0 + ii) * 3;
        bdp0 = sp[0]; bdp1 = sp[1]; bdp2 = sp[2];
        float* dp2 = &BD[(ii * 16 + jj) * 4];
        dp2[0] = bdp0; dp2[1] = bdp1; dp2[2] = bdp2;
    }

    f32x4 oacc[8][2];
#pragma unroll
    for (int a = 0; a < 8; ++a)
#pragma unroll
        for (int c = 0; c < 2; ++c) oacc[a][c] = (f32x4){0.f, 0.f, 0.f, 0.f};
    float dn[4][4] = {};
    float dd[4][3][2] = {};

    __syncthreads();   // W1B + BD(pass0) visible; prologue prefetch drained

#pragma clang loop unroll(disable)
    for (int ps = 0; ps < 8; ++ps) {
        const int jg0 = jq * 128 + ps * 16;

        // ---- P1: sim (MFMA) -> ES (pure compute: operands in registers) ----
        {
            bf16x8 cqk_use[8];
#pragma unroll
            for (int hh = 0; hh < 8; ++hh) cqk_use[hh] = cqk_pf[hh];
#pragma unroll
            for (int hh = 0; hh < 4; ++hh) {
                const int h0 = wv * 8 + hh * 2;
                f32x4 c0 = (f32x4){0.f, 0.f, 0.f, 0.f}, c1 = c0;
                c0 = MFMA_BF16(qkf[hh * 2],     cqk_use[hh * 2],     c0, 0, 0, 0);
                c1 = MFMA_BF16(qkf[hh * 2 + 1], cqk_use[hh * 2 + 1], c1, 0, 0, 0);
#pragma unroll
                for (int r = 0; r < 4; ++r)
                    *(u32*)&ES[((qd * 4 + r) * 16 + ln) * 40 + h0] = cvt_pk_bf16(c0[r], c1[r]);
            }
        }
        __syncthreads();   // P1-end

        // ---- P2 top: issue pass ps+1 prefetch (arrival forced by the
        //      vmcnt(0) drain at the post-P2 barrier) ----
        const int psn = (ps < 7) ? ps + 1 : 7;   // clamp: avoid OOB prefetch
        const int jgn = jq * 128 + psn * 16;
        float4 bde_use[8];
#pragma unroll
        for (int k = 0; k < 8; ++k) bde_use[k] = bde_pf[k];
        {
            const u16* crow = cqk + (size_t)(b * 512 + jgn + ln) * 1024 + qd * 8;
#pragma unroll
            for (int hh = 0; hh < 8; ++hh)
                cqk_pf[hh] = *(const bf16x8*)(crow + (wv * 8 + hh) * 32);
#pragma unroll
            for (int s2 = 0; s2 < 4; ++s2) {
                const float* dps = bde + (((size_t)(b * 512 + jgn + ln)) * 128 + i0 + wv * 4 + s2) * 32 + qd * 8;
                bde_pf[s2 * 2]     = ((const float4*)dps)[0];
                bde_pf[s2 * 2 + 1] = ((const float4*)dps)[1];
            }
            const float* sp = bdis + ((size_t)(b * 512 + jgn + jj) * 128 + i0 + ii) * 3;
            bdp0 = sp[0]; bdp1 = sp[1]; bdp2 = sp[2];
        }

        // ---- P2: per s (i = wv*4+s): MLP1 -> mish -> MLP2 -> exp2 -> Estage ----
#pragma unroll
        for (int s = 0; s < 4; ++s) {
            const int i_loc = wv * 4 + s;
            bf16x8 af0 = *(const bf16x8*)&ES[(i_loc * 16 + ln) * 40 + qd * 8];
            bf16x8 af1;
            {
                float4 a0 = bde_use[s * 2];
                float4 a1 = bde_use[s * 2 + 1];
                uint4 u;
                u.x = cvt_pk_bf16(a0.x, a0.y);
                u.y = cvt_pk_bf16(a0.z, a0.w);
                u.z = cvt_pk_bf16(a1.x, a1.y);
                u.w = cvt_pk_bf16(a1.z, a1.w);
                af1 = __builtin_bit_cast(bf16x8, u);
            }
            f32x4 uacc[4];
#pragma unroll
            for (int ot = 0; ot < 4; ++ot) uacc[ot] = (f32x4){0.f, 0.f, 0.f, 0.f};
#pragma unroll
            for (int cg = 0; cg < 4; ++cg) {
                u16* mtp = MT + wv * 1280 + (cg & 1) * 640;   // cg-parity dbuf
                bf16x8 w00 = *(const bf16x8*)&W1B[((cg * 2 + 0) * 64 + lane) * 8];
                bf16x8 w01 = *(const bf16x8*)&W1B[((cg * 2 + 1) * 64 + lane) * 8];
                bf16x8 w10 = *(const bf16x8*)&W1B[((8 + cg * 2 + 0) * 64 + lane) * 8];
                bf16x8 w11 = *(const bf16x8*)&W1B[((8 + cg * 2 + 1) * 64 + lane) * 8];
                f32x4 t0 = (f32x4){0.f, 0.f, 0.f, 0.f}, t1 = t0;
                t0 = MFMA_BF16(af0, w00, t0, 0, 0, 0);
                t0 = MFMA_BF16(af1, w10, t0, 0, 0, 0);
                t1 = MFMA_BF16(af0, w01, t1, 0, 0, 0);
                t1 = MFMA_BF16(af1, w11, t1, 0, 0, 0);
                // packed mish pair -> one ds_write_b32; u16 slot 2m holds ch m,
                // slot 2m+1 holds ch 16+m (w2b K-order permuted to match)
#pragma unroll
                for (int r = 0; r < 4; ++r) {
                    u32 pk = cvt_pk_bf16(mishf(t0[r]), mishf(t1[r]));
                    *(u32*)&mtp[(qd * 4 + r) * 40 + (ln << 1)] = pk;
                }
                bf16x8 ta = *(const bf16x8*)&mtp[ln * 40 + qd * 8];
#pragma unroll
                for (int ot = 0; ot < 4; ++ot) {
                    bf16x8 wf = *(const bf16x8*)(w2b + ((size_t)(cg * 4 + ot) * 64 + lane) * 8);
                    uacc[ot] = MFMA_BF16(ta, wf, uacc[ot], 0, 0, 0);
                }
            }
            float Ev[4][4];
#pragma unroll
            for (int ot = 0; ot < 4; ++ot) {
#pragma unroll
                for (int r = 0; r < 4; ++r) Ev[ot][r] = exp2_asm(uacc[ot][r] + b2r[ot]);
                dn[s][ot] += (Ev[ot][0] + Ev[ot][1]) + (Ev[ot][2] + Ev[ot][3]);
            }
#pragma unroll
            for (int r = 0; r < 4; ++r) {
                float4 bp = *(const float4*)&BD[(i_loc * 16 + qd * 4 + r) * 4];
                dd[s][0][0] += Ev[2][r] * bp.x; dd[s][0][1] += Ev[3][r] * bp.x;
                dd[s][1][0] += Ev[2][r] * bp.y; dd[s][1][1] += Ev[3][r] * bp.y;
                dd[s][2][0] += Ev[2][r] * bp.z; dd[s][2][1] += Ev[3][r] * bp.z;
            }
#pragma unroll
            for (int ot = 0; ot < 2; ++ot) {
                const int base = (ot * 16 + ln) * 392 + i_loc * 24 + qd * 4;
                *(u32*)&EST[base]     = cvt_pk_bf16(Ev[ot][0], Ev[ot][1]);
                *(u32*)&EST[base + 2] = cvt_pk_bf16(Ev[ot][2], Ev[ot][3]);
            }
        }
        __syncthreads();   // P2-end

        // ---- P3: PV via MFMA + BD refill for pass ps+1.
        //      No trailing barrier: EST rewrite is in next P2, reachable only
        //      via next P1-end barrier; BD read in next P2 likewise. ----
        {
            float* dp2 = &BD[(ii * 16 + jj) * 4];
            dp2[0] = bdp0; dp2[1] = bdp1; dp2[2] = bdp2;
        }
#pragma unroll
        for (int hh = 0; hh < 8; ++hh) {
            const int h = wv * 8 + hh;
            bf16x8 af = (bf16x8){0, 0, 0, 0, 0, 0, 0, 0};
            if (qd < 2) af = *(const bf16x8*)&EST[h * 392 + ln * 24 + qd * 8];
#pragma unroll
            for (int nt = 0; nt < 2; ++nt) {
                bf16x8 bfr = (bf16x8){0, 0, 0, 0, 0, 0, 0, 0};
                if (qd < 2)
                    bfr = *(const bf16x8*)(cvT + ((size_t)(b * 1024 + h * 32 + nt * 16 + ln)) * 512 + jg0 + qd * 8);
                oacc[hh][nt] = MFMA_BF16(af, bfr, oacc[hh][nt], 0, 0, 0);
            }
        }
    }

    // ---- epilogue: write partials ----
    float* P = partial + (size_t)pidx * 18944;
#pragma unroll
    for (int hh = 0; hh < 8; ++hh)
#pragma unroll
        for (int nt = 0; nt < 2; ++nt)
#pragma unroll
            for (int r = 0; r < 4; ++r)
                P[(size_t)(qd * 4 + r) * 1024 + (wv * 8 + hh) * 32 + nt * 16 + ln] = oacc[hh][nt][r];
#pragma unroll
    for (int s = 0; s < 4; ++s)
#pragma unroll
        for (int ot = 0; ot < 4; ++ot) {
            float v = dn[s][ot];
            v += __shfl_xor(v, 16, 64);
            v += __shfl_xor(v, 32, 64);
            if (qd == 0) P[16384 + (wv * 4 + s) * 64 + ot * 16 + ln] = v;
        }
#pragma unroll
    for (int s = 0; s < 4; ++s)
#pragma unroll
        for (int d = 0; d < 3; ++d)
#pragma unroll
            for (int o = 0; o < 2; ++o) {
                float v = dd[s][d][o];
                v += __shfl_xor(v, 16, 64);
                v += __shfl_xor(v, 32, 64);
                if (qd == 0) P[17408 + (wv * 4 + s) * 96 + d * 32 + o * 16 + ln] = v;
            }
}

// ---------------------------------------------------------------------------
// finalize: per (b,it): combine 4 jq partials, normalize, Wo epilogue (MFMA),
// dis-MLP. 128 blocks x 256 threads.
// ---------------------------------------------------------------------------
__global__ __launch_bounds__(256, 2) void finalize(
    const float* __restrict__ partial, const u16* __restrict__ WoT,
    const float* __restrict__ bo,
    const float* __restrict__ Wd1, const float* __restrict__ bd1,
    const float* __restrict__ Wd2, const float* __restrict__ bd2,
    float* __restrict__ out0, float* __restrict__ out1)
{
    __shared__ float denomL[1024];
    __shared__ u16 preL[16 * 1032];
    __shared__ float odisL[1536];
    __shared__ float r1L[3072];

    const int tid = threadIdx.x;
    const int f = blockIdx.x;
    const int b = f >> 3, it = f & 7;
    const int row0 = b * 128 + it * 16;
    const float* P0 = partial + (size_t)(f * 4 + 0) * 18944;
    const float* P1 = partial + (size_t)(f * 4 + 1) * 18944;
    const float* P2 = partial + (size_t)(f * 4 + 2) * 18944;
    const float* P3 = partial + (size_t)(f * 4 + 3) * 18944;

    for (int k = tid; k < 1024; k += 256)
        denomL[k] = P0[16384 + k] + P1[16384 + k] + P2[16384 + k] + P3[16384 + k];
    __syncthreads();

    {
        const int h = tid >> 3;
#pragma unroll
        for (int i = 0; i < 16; ++i) {
            float4 a = *(const float4*)&P0[(size_t)i * 1024 + tid * 4];
            float4 bq = *(const float4*)&P1[(size_t)i * 1024 + tid * 4];
            float4 c = *(const float4*)&P2[(size_t)i * 1024 + tid * 4];
            float4 d = *(const float4*)&P3[(size_t)i * 1024 + tid * 4];
            float rdn = 1.f / denomL[i * 64 + h];
            u32 p0 = cvt_pk_bf16((a.x + bq.x + c.x + d.x) * rdn, (a.y + bq.y + c.y + d.y) * rdn);
            u32 p1 = cvt_pk_bf16((a.z + bq.z + c.z + d.z) * rdn, (a.w + bq.w + c.w + d.w) * rdn);
            *(uint2*)(void*)&preL[i * 1032 + tid * 4] = make_uint2(p0, p1);
        }
    }
    for (int idx = tid; idx < 1536; idx += 256) {
        int i = idx / 96, rm = idx % 96, h = rm & 31;
        odisL[idx] = (P0[17408 + idx] + P1[17408 + idx] + P2[17408 + idx] + P3[17408 + idx])
                     / denomL[i * 64 + 32 + h];
    }
    __syncthreads();

    {
        const int lane = tid & 63, wv = tid >> 6;
        const int qd = lane >> 4, ln = lane & 15;
        f32x4 acc[4];
#pragma unroll
        for (int nt = 0; nt < 4; ++nt) acc[nt] = (f32x4){0.f, 0.f, 0.f, 0.f};
#pragma clang loop unroll(disable)
        for (int ks = 0; ks < 32; ++ks) {
            bf16x8 af = *(const bf16x8*)&preL[ln * 1032 + ks * 32 + qd * 8];
#pragma unroll
            for (int nt = 0; nt < 4; ++nt) {
                bf16x8 wf = *(const bf16x8*)(WoT + ((size_t)(wv * 64 + nt * 16 + ln)) * 1024 + ks * 32 + qd * 8);
                acc[nt] = MFMA_BF16(af, wf, acc[nt], 0, 0, 0);
            }
        }
#pragma unroll
        for (int nt = 0; nt < 4; ++nt) {
            int col = wv * 64 + nt * 16 + ln;
            float bv = bo[col];
#pragma unroll
            for (int r = 0; r < 4; ++r)
                out0[(size_t)(row0 + qd * 4 + r) * 256 + col] = acc[nt][r] + bv;
        }
    }

    for (int idx = tid; idx < 3072; idx += 256) {
        int i = idx / 192, rm = idx % 192, d = rm / 64, c = rm & 63;
        float t = bd1[c];
#pragma unroll
        for (int hh = 0; hh < 32; ++hh)
            t += odisL[i * 96 + d * 32 + hh] * Wd1[hh * 64 + c];
        r1L[idx] = mishf(t);
    }
    __syncthreads();
    for (int idx = tid; idx < 1536; idx += 256) {
        int i = idx / 96, rm = idx % 96, d = rm >> 5, h = rm & 31;
        float v = bd2[h];
#pragma unroll
        for (int c = 0; c < 64; ++c)
            v += r1L[i * 192 + d * 64 + c] * Wd2[c * 32 + h];
        out1[(size_t)(row0 + i) * 96 + d * 32 + h] = v;
    }
}

extern "C" void kernel_launch(void* const* d_in, const int* in_sizes, int n_in,
                              void* d_out, int out_size, void* d_ws, size_t ws_size,
                              hipStream_t stream) {
    const float* x    = (const float*)d_in[0];
    const float* ctx  = (const float*)d_in[1];
    const float* bdis = (const float*)d_in[2];
    const float* bde  = (const float*)d_in[3];
    const float* Wqk  = (const float*)d_in[6];
    const float* Wcqk = (const float*)d_in[8];
    const float* Wcv  = (const float*)d_in[9];
    const float* Wm1  = (const float*)d_in[10];
    const float* Wm2  = (const float*)d_in[11];
    const float* bm2  = (const float*)d_in[12];
    const float* Wo   = (const float*)d_in[13];
    const float* bo   = (const float*)d_in[14];
    const float* Wd1  = (const float*)d_in[15];
    const float* bd1  = (const float*)d_in[16];
    const float* Wd2  = (const float*)d_in[17];
    const float* bd2  = (const float*)d_in[18];

    char* ws = (char*)d_ws;
    u16* qk_ws  = (u16*)(ws);                       // 4 MB
    u16* cqk_ws = (u16*)(ws + 4194304);             // 16 MB
    u16* cvT_ws = (u16*)(ws + 20971520);            // 16 MB
    u16* w1b    = (u16*)(ws + 37748736);            // 16 KB
    u16* w2b    = (u16*)(ws + 37765120);            // 16 KB
    u16* WoT    = (u16*)(ws + 37781504);            // 512 KB
    float* part = (float*)(ws + 38305792);          // 512*18944*4 = 38.8 MB
    u16* cv_rm  = (u16*)(ws + 38305792);            // 16 MB overlay (dead before part)

    float* out0 = (float*)d_out;
    float* out1 = out0 + (size_t)2048 * 256;

    const float SCALE = 0.17677669529663687f;       // 32^-0.5, folded into qk

    prep<<<257, 256, 0, stream>>>(Wo, Wm1, Wm2, WoT, w1b, w2b);
    gemm_mfma<<<dim3(8, 16), 256, 0, stream>>>(x,   Wqk,  qk_ws,  2048, 1024, 256, SCALE);
    gemm_mfma<<<dim3(8, 64), 256, 0, stream>>>(ctx, Wcqk, cqk_ws, 8192, 1024, 256, 1.0f);
    gemm_mfma<<<dim3(8, 64), 256, 0, stream>>>(ctx, Wcv,  cv_rm,  8192, 1024, 256, 1.0f);
    transpose_cv<<<dim3(16, 8, 16), 256, 0, stream>>>(cv_rm, cvT_ws);
    attn5<<<512, 256, 0, stream>>>(qk_ws, cqk_ws, cvT_ws, bde, bdis, w1b, w2b, bm2, part);
    finalize<<<128, 256, 0, stream>>>(part, WoT, bo, Wd1, bd1, Wd2, bd2, out0, out1);
}

// Round 8
// 506.438 us; speedup vs baseline: 1.2040x; 1.0614x over previous
//
#include <hip/hip_runtime.h>

typedef unsigned short u16;
typedef unsigned int   u32;
typedef __attribute__((ext_vector_type(8))) short bf16x8;
typedef __attribute__((ext_vector_type(4))) float f32x4;

#define MFMA_BF16 __builtin_amdgcn_mfma_f32_16x16x32_bf16
#define LOG2E 1.4426950408889634f

__device__ __forceinline__ u16 f2bf(float f) {
    u32 x = __builtin_bit_cast(u32, f);
    u32 r = (x + 0x7fffu + ((x >> 16) & 1u)) >> 16;
    return (u16)r;
}
// one-instruction pack: dst.lo = bf16(lo), dst.hi = bf16(hi)  (RNE)
__device__ __forceinline__ u32 cvt_pk_bf16(float lo, float hi) {
    u32 r;
    asm("v_cvt_pk_bf16_f32 %0, %1, %2" : "=v"(r) : "v"(lo), "v"(hi));
    return r;
}
__device__ __forceinline__ float exp2_asm(float x) {
    float r;
    asm("v_exp_f32 %0, %1" : "=v"(r) : "v"(x));
    return r;
}
__device__ __forceinline__ float rcp_asm(float x) {
    float r;
    asm("v_rcp_f32 %0, %1" : "=v"(r) : "v"(x));
    return r;
}
// mish(x) = x * (p^2-1)/(p^2+1), p = 1+e^x. Written as x*(1 - 2/(p^2+1)):
// graceful at both infinities (e=0 -> r=0; e=inf -> r=1), no cmp/sel, no div.
__device__ __forceinline__ float mishf(float x) {
    float e = exp2_asm(x * LOG2E);
    float p = 1.f + e;
    float d = __builtin_fmaf(p, p, 1.f);
    float r = __builtin_fmaf(-2.f, rcp_asm(d), 1.f);
    return x * r;
}

// ---------------------------------------------------------------------------
// proj_fused: R8. The 272-us non-attn residue was invariant to GEMM tile
// width (R7 falsifier) -> it is launch serialization + shuffle traffic, not
// GEMM staging. Fuse prep + 3 GEMMs + transpose_cv into ONE launch:
//   blk [0,128)    : qk  = x @ Wqk  (scale folded), 128x128 tile
//   blk [128,640)  : cqk = ctx @ Wcqk
//   blk [640,1152) : cv  = ctx @ Wcv, epilogue transposes in LDS and writes
//                    cvT directly (kills the 33.6 MB cv->HBM->transpose trip)
//   blk [1152,1409): prep (WoT / w1b / w2b swizzles)
// Branch is block-uniform -> barrier-safe. Small grids overlap big ones.
// ---------------------------------------------------------------------------
__global__ __launch_bounds__(256) void proj_fused(
    const float* __restrict__ x,   const float* __restrict__ Wqk,  u16* __restrict__ qk_ws,
    const float* __restrict__ ctx, const float* __restrict__ Wcqk, u16* __restrict__ cqk_ws,
    const float* __restrict__ Wcv, u16* __restrict__ cvT,
    const float* __restrict__ Wo,  const float* __restrict__ W1,   const float* __restrict__ W2,
    u16* __restrict__ WoT, u16* __restrict__ w1b, u16* __restrict__ w2b,
    float scale)
{
    __shared__ __align__(16) char smem[18432];
    const int id = blockIdx.x;
    const int tid = threadIdx.x;

    if (id >= 1152) {            // ---- prep branch ----
        const int bb = id - 1152, t = tid;
        if (bb < 256) {
#pragma unroll
            for (int kk = 0; kk < 4; ++kk)
                WoT[(size_t)t * 1024 + bb * 4 + kk] = f2bf(Wo[(size_t)(bb * 4 + kk) * 256 + t]);
        } else {
            for (int u = 0; u < 32; ++u) {        // W1: frag f = ks*8+nt
                int idx = t + 256 * u;
                int j = idx & 7, lane = (idx >> 3) & 63, f = idx >> 9;
                int n = lane & 15, q = lane >> 4, ntc = f & 7, ks = f >> 3;
                w1b[idx] = f2bf(W1[(ks * 32 + q * 8 + j) * 128 + ntc * 16 + n]);
            }
            for (int u = 0; u < 32; ++u) {        // W2: frag f = ks*4+ot, K-perm + log2e
                int idx = t + 256 * u;
                int j = idx & 7, lane = (idx >> 3) & 63, f = idx >> 9;
                int n = lane & 15, q = lane >> 4, ot = f & 3, ks = f >> 2;
                int k = q * 8 + j;
                int ch = ((k & 1) << 4) | (k >> 1);
                w2b[idx] = f2bf(W2[(ks * 32 + ch) * 64 + ot * 16 + n] * LOG2E);
            }
        }
        return;
    }

    // ---- GEMM branches: C[M,1024] = A[M,256] @ W[256,1024], 128x128 tile ----
    u16* As = (u16*)smem;                 // 10240 B
    u16* Bf = (u16*)(smem + 10240);       //  8192 B

    const float* A; const float* W; u16* C = qk_ws;
    int bx, by; bool cv = false; float sc = 1.0f;
    if (id < 128)      { A = x;   W = Wqk;  C = qk_ws;  bx = id & 7; by = id >> 3; sc = scale; }
    else if (id < 640) { A = ctx; W = Wcqk; C = cqk_ws; int i2 = id - 128; bx = i2 & 7; by = i2 >> 3; }
    else               { A = ctx; W = Wcv;              int i2 = id - 640; bx = i2 & 7; by = i2 >> 3; cv = true; }

    const int K = 256, N = 1024;
    const int lane = tid & 63, wv = tid >> 6;
    const int qd = lane >> 4, ln = lane & 15;
    const int m0 = by * 128, n0 = bx * 128;

    f32x4 acc[2][8];
#pragma unroll
    for (int a = 0; a < 2; ++a)
#pragma unroll
        for (int nt = 0; nt < 8; ++nt) acc[a][nt] = (f32x4){0.f, 0.f, 0.f, 0.f};

    for (int k0 = 0; k0 < K; k0 += 32) {
        {
            int r = tid >> 1, kh = (tid & 1) * 16;
            const float* ap = A + (size_t)(m0 + r) * K + k0 + kh;
            float4 a0 = ((const float4*)ap)[0];
            float4 a1 = ((const float4*)ap)[1];
            float4 a2 = ((const float4*)ap)[2];
            float4 a3 = ((const float4*)ap)[3];
            uint4 p0, p1;
            p0.x = cvt_pk_bf16(a0.x, a0.y);
            p0.y = cvt_pk_bf16(a0.z, a0.w);
            p0.z = cvt_pk_bf16(a1.x, a1.y);
            p0.w = cvt_pk_bf16(a1.z, a1.w);
            p1.x = cvt_pk_bf16(a2.x, a2.y);
            p1.y = cvt_pk_bf16(a2.z, a2.w);
            p1.z = cvt_pk_bf16(a3.x, a3.y);
            p1.w = cvt_pk_bf16(a3.z, a3.w);
            *(uint4*)&As[r * 40 + kh]     = p0;
            *(uint4*)&As[r * 40 + kh + 8] = p1;
        }
        {
            int ntA = tid >> 6, q = (tid >> 4) & 3, nn = tid & 15;
#pragma unroll
            for (int h = 0; h < 2; ++h) {
                int nt = ntA + h * 4;
                const float* wp = W + (size_t)(k0 + q * 8) * N + n0 + nt * 16 + nn;
                float w0 = wp[0], w1 = wp[(size_t)1 * N], w2 = wp[(size_t)2 * N], w3 = wp[(size_t)3 * N];
                float w4 = wp[(size_t)4 * N], w5 = wp[(size_t)5 * N], w6 = wp[(size_t)6 * N], w7 = wp[(size_t)7 * N];
                uint4 u;
                u.x = cvt_pk_bf16(w0, w1);
                u.y = cvt_pk_bf16(w2, w3);
                u.z = cvt_pk_bf16(w4, w5);
                u.w = cvt_pk_bf16(w6, w7);
                *(uint4*)&Bf[(nt * 64 + q * 16 + nn) * 8] = u;
            }
        }
        __syncthreads();
        bf16x8 af0 = *(const bf16x8*)&As[(wv * 32 + ln) * 40 + qd * 8];
        bf16x8 af1 = *(const bf16x8*)&As[(wv * 32 + 16 + ln) * 40 + qd * 8];
#pragma unroll
        for (int nt = 0; nt < 8; ++nt) {
            bf16x8 bfr = *(const bf16x8*)&Bf[(nt * 64 + lane) * 8];
            acc[0][nt] = MFMA_BF16(af0, bfr, acc[0][nt], 0, 0, 0);
            acc[1][nt] = MFMA_BF16(af1, bfr, acc[1][nt], 0, 0, 0);
        }
        __syncthreads();
    }

    if (!cv) {
        // ---- row-major C write (qk / cqk) ----
#pragma unroll
        for (int a = 0; a < 2; ++a)
#pragma unroll
            for (int nt = 0; nt < 8; ++nt) {
                u32 pk0 = cvt_pk_bf16(acc[a][nt][0] * sc, acc[a][nt][1] * sc);
                u32 pk1 = cvt_pk_bf16(acc[a][nt][2] * sc, acc[a][nt][3] * sc);
                size_t base = (size_t)(m0 + wv * 32 + a * 16 + qd * 4) * N + n0 + nt * 16 + ln;
                C[base]               = (u16)pk0;
                C[base + (size_t)N]   = (u16)(pk0 >> 16);
                C[base + (size_t)2*N] = (u16)pk1;
                C[base + (size_t)3*N] = (u16)(pk1 >> 16);
            }
    } else {
        // ---- cv: transpose in LDS, write cvT[(b*1024+ch)*512 + j] directly.
        // Tile rows = j (within one b: 512 j per b, m0 128-aligned), cols = ch.
        // Two 64-ch halves through T[64][136] (17.4 KB, reuses As/Bf). ----
        const int b = m0 >> 9, jt = m0 & 511;
        u16* T = (u16*)smem;
#pragma unroll
        for (int h = 0; h < 2; ++h) {
            if (h) __syncthreads();   // h=0 safe: K-loop ended with a barrier
#pragma unroll
            for (int a = 0; a < 2; ++a)
#pragma unroll
                for (int t2 = 0; t2 < 4; ++t2) {
                    int nt = h * 4 + t2;
                    int chl = t2 * 16 + ln;
                    int row = wv * 32 + a * 16 + qd * 4;
                    uint2 pk;
                    pk.x = cvt_pk_bf16(acc[a][nt][0], acc[a][nt][1]);
                    pk.y = cvt_pk_bf16(acc[a][nt][2], acc[a][nt][3]);
                    *(uint2*)&T[chl * 136 + row] = pk;
                }
            __syncthreads();
            {
                int chl = tid >> 2, jseg = (tid & 3) * 32;
                const uint4* src = (const uint4*)&T[chl * 136 + jseg];
                u16* dst = cvT + ((size_t)(b * 1024 + n0 + h * 64 + chl)) * 512 + jt + jseg;
                ((uint4*)dst)[0] = src[0];
                ((uint4*)dst)[1] = src[1];
                ((uint4*)dst)[2] = src[2];
                ((uint4*)dst)[3] = src[3];
            }
        }
    }
}

// ---------------------------------------------------------------------------
// attn10 (unchanged from R7, verified 264.6 us): register-rich cross-pass
// prefetch at 1 wave/SIMD, full-size 16 KB W1B, 2 barriers/pass.
// R6 lesson locked in: >1 wave/SIMD loses more ILP than TLP repays.
// ---------------------------------------------------------------------------
__global__ __launch_bounds__(256, 1) void attn5(
    const u16* __restrict__ qk,      // [2048][1024] bf16 (scale folded)
    const u16* __restrict__ cqk,     // [8192][1024] bf16
    const u16* __restrict__ cvT,     // [16][1024][512] bf16
    const float* __restrict__ bde,   // [16][512][128][32]
    const float* __restrict__ bdis,  // [16][512][128][3]
    const u16* __restrict__ w1b, const u16* __restrict__ w2b,
    const float* __restrict__ b2,
    float* __restrict__ partial)
{
    __shared__ __align__(16) char smem[76288];
    u16*   ES  = (u16*)smem;             // 20480 B: [256 rows=(i*16+j)][40]
    u16*   MT  = (u16*)(smem + 20480);   // 10240 B: per-wave miniT, cg-dbuf
    float* BD  = (float*)(smem + 30720); //  4096 B: bdis stage [16 i][16 j][4]
    u16*   EST = (u16*)(smem + 34816);   // 25088 B: Estage [32 h][16 i][24+pad]
    u16*   W1B = (u16*)(smem + 59904);   // 16384 B: W1 frags (full size)

    const int tid = threadIdx.x;
    const int lane = tid & 63, wv = tid >> 6;
    const int qd = lane >> 4, ln = lane & 15;
    const int nblk = blockIdx.x;
    const int xcd = nblk & 7, g = nblk >> 3;
    const int b = xcd * 2 + (g & 1);
    const int r2 = g >> 1;
    const int it = r2 >> 2, jq = r2 & 3;
    const int i0 = it * 16;
    const int pidx = (b * 8 + it) * 4 + jq;

    for (int k = tid; k < 4096; k += 256) ((u32*)W1B)[k] = ((const u32*)w1b)[k];

    float b2r[4];
#pragma unroll
    for (int ot = 0; ot < 4; ++ot) b2r[ot] = b2[ot * 16 + ln] * LOG2E;

    // qk A-frags: registers for the whole kernel (same i-tile every pass)
    bf16x8 qkf[8];
#pragma unroll
    for (int hh = 0; hh < 8; ++hh) {
        int h = wv * 8 + hh;
        qkf[hh] = *(const bf16x8*)(qk + ((size_t)(b * 128 + i0 + ln)) * 1024 + h * 32 + qd * 8);
    }

    const int ii = tid & 15, jj = tid >> 4;   // bdis stage mapping

    // ---- prologue: prefetch pass-0 inputs ----
    bf16x8 cqk_pf[8];
    float4 bde_pf[8];
    float bdp0, bdp1, bdp2;
    {
        const u16* crow = cqk + (size_t)(b * 512 + jq * 128 + ln) * 1024 + qd * 8;
#pragma unroll
        for (int hh = 0; hh < 8; ++hh)
            cqk_pf[hh] = *(const bf16x8*)(crow + (wv * 8 + hh) * 32);
#pragma unroll
        for (int s2 = 0; s2 < 4; ++s2) {
            const float* dps = bde + (((size_t)(b * 512 + jq * 128 + ln)) * 128 + i0 + wv * 4 + s2) * 32 + qd * 8;
            bde_pf[s2 * 2]     = ((const float4*)dps)[0];
            bde_pf[s2 * 2 + 1] = ((const float4*)dps)[1];
        }
        const float* sp = bdis + ((size_t)(b * 512 + jq * 128 + jj) * 128 + i0 + ii) * 3;
        bdp0 = sp[0]; bdp1 = sp[1]; bdp2 = sp[2];
        float* dp2 = &BD[(ii * 16 + jj) * 4];
        dp2[0] = bdp0; dp2[1] = bdp1; dp2[2] = bdp2;
    }

    f32x4 oacc[8][2];
#pragma unroll
    for (int a = 0; a < 8; ++a)
#pragma unroll
        for (int c = 0; c < 2; ++c) oacc[a][c] = (f32x4){0.f, 0.f, 0.f, 0.f};
    float dn[4][4] = {};
    float dd[4][3][2] = {};

    __syncthreads();   // W1B + BD(pass0) visible; prologue prefetch drained

#pragma clang loop unroll(disable)
    for (int ps = 0; ps < 8; ++ps) {
        const int jg0 = jq * 128 + ps * 16;

        // ---- P1: sim (MFMA) -> ES (pure compute: operands in registers) ----
        {
            bf16x8 cqk_use[8];
#pragma unroll
            for (int hh = 0; hh < 8; ++hh) cqk_use[hh] = cqk_pf[hh];
#pragma unroll
            for (int hh = 0; hh < 4; ++hh) {
                const int h0 = wv * 8 + hh * 2;
                f32x4 c0 = (f32x4){0.f, 0.f, 0.f, 0.f}, c1 = c0;
                c0 = MFMA_BF16(qkf[hh * 2],     cqk_use[hh * 2],     c0, 0, 0, 0);
                c1 = MFMA_BF16(qkf[hh * 2 + 1], cqk_use[hh * 2 + 1], c1, 0, 0, 0);
#pragma unroll
                for (int r = 0; r < 4; ++r)
                    *(u32*)&ES[((qd * 4 + r) * 16 + ln) * 40 + h0] = cvt_pk_bf16(c0[r], c1[r]);
            }
        }
        __syncthreads();   // P1-end

        // ---- P2 top: issue pass ps+1 prefetch (arrival forced by the
        //      vmcnt(0) drain at the post-P2 barrier) ----
        const int psn = (ps < 7) ? ps + 1 : 7;   // clamp: avoid OOB prefetch
        const int jgn = jq * 128 + psn * 16;
        float4 bde_use[8];
#pragma unroll
        for (int k = 0; k < 8; ++k) bde_use[k] = bde_pf[k];
        {
            const u16* crow = cqk + (size_t)(b * 512 + jgn + ln) * 1024 + qd * 8;
#pragma unroll
            for (int hh = 0; hh < 8; ++hh)
                cqk_pf[hh] = *(const bf16x8*)(crow + (wv * 8 + hh) * 32);
#pragma unroll
            for (int s2 = 0; s2 < 4; ++s2) {
                const float* dps = bde + (((size_t)(b * 512 + jgn + ln)) * 128 + i0 + wv * 4 + s2) * 32 + qd * 8;
                bde_pf[s2 * 2]     = ((const float4*)dps)[0];
                bde_pf[s2 * 2 + 1] = ((const float4*)dps)[1];
            }
            const float* sp = bdis + ((size_t)(b * 512 + jgn + jj) * 128 + i0 + ii) * 3;
            bdp0 = sp[0]; bdp1 = sp[1]; bdp2 = sp[2];
        }

        // ---- P2: per s (i = wv*4+s): MLP1 -> mish -> MLP2 -> exp2 -> Estage ----
#pragma unroll
        for (int s = 0; s < 4; ++s) {
            const int i_loc = wv * 4 + s;
            bf16x8 af0 = *(const bf16x8*)&ES[(i_loc * 16 + ln) * 40 + qd * 8];
            bf16x8 af1;
            {
                float4 a0 = bde_use[s * 2];
                float4 a1 = bde_use[s * 2 + 1];
                uint4 u;
                u.x = cvt_pk_bf16(a0.x, a0.y);
                u.y = cvt_pk_bf16(a0.z, a0.w);
                u.z = cvt_pk_bf16(a1.x, a1.y);
                u.w = cvt_pk_bf16(a1.z, a1.w);
                af1 = __builtin_bit_cast(bf16x8, u);
            }
            f32x4 uacc[4];
#pragma unroll
            for (int ot = 0; ot < 4; ++ot) uacc[ot] = (f32x4){0.f, 0.f, 0.f, 0.f};
#pragma unroll
            for (int cg = 0; cg < 4; ++cg) {
                u16* mtp = MT + wv * 1280 + (cg & 1) * 640;   // cg-parity dbuf
                bf16x8 w00 = *(const bf16x8*)&W1B[((cg * 2 + 0) * 64 + lane) * 8];
                bf16x8 w01 = *(const bf16x8*)&W1B[((cg * 2 + 1) * 64 + lane) * 8];
                bf16x8 w10 = *(const bf16x8*)&W1B[((8 + cg * 2 + 0) * 64 + lane) * 8];
                bf16x8 w11 = *(const bf16x8*)&W1B[((8 + cg * 2 + 1) * 64 + lane) * 8];
                f32x4 t0 = (f32x4){0.f, 0.f, 0.f, 0.f}, t1 = t0;
                t0 = MFMA_BF16(af0, w00, t0, 0, 0, 0);
                t0 = MFMA_BF16(af1, w10, t0, 0, 0, 0);
                t1 = MFMA_BF16(af0, w01, t1, 0, 0, 0);
                t1 = MFMA_BF16(af1, w11, t1, 0, 0, 0);
                // packed mish pair -> one ds_write_b32; u16 slot 2m holds ch m,
                // slot 2m+1 holds ch 16+m (w2b K-order permuted to match)
#pragma unroll
                for (int r = 0; r < 4; ++r) {
                    u32 pk = cvt_pk_bf16(mishf(t0[r]), mishf(t1[r]));
                    *(u32*)&mtp[(qd * 4 + r) * 40 + (ln << 1)] = pk;
                }
                bf16x8 ta = *(const bf16x8*)&mtp[ln * 40 + qd * 8];
#pragma unroll
                for (int ot = 0; ot < 4; ++ot) {
                    bf16x8 wf = *(const bf16x8*)(w2b + ((size_t)(cg * 4 + ot) * 64 + lane) * 8);
                    uacc[ot] = MFMA_BF16(ta, wf, uacc[ot], 0, 0, 0);
                }
            }
            float Ev[4][4];
#pragma unroll
            for (int ot = 0; ot < 4; ++ot) {
#pragma unroll
                for (int r = 0; r < 4; ++r) Ev[ot][r] = exp2_asm(uacc[ot][r] + b2r[ot]);
                dn[s][ot] += (Ev[ot][0] + Ev[ot][1]) + (Ev[ot][2] + Ev[ot][3]);
            }
#pragma unroll
            for (int r = 0; r < 4; ++r) {
                float4 bp = *(const float4*)&BD[(i_loc * 16 + qd * 4 + r) * 4];
                dd[s][0][0] += Ev[2][r] * bp.x; dd[s][0][1] += Ev[3][r] * bp.x;
                dd[s][1][0] += Ev[2][r] * bp.y; dd[s][1][1] += Ev[3][r] * bp.y;
                dd[s][2][0] += Ev[2][r] * bp.z; dd[s][2][1] += Ev[3][r] * bp.z;
            }
#pragma unroll
            for (int ot = 0; ot < 2; ++ot) {
                const int base = (ot * 16 + ln) * 392 + i_loc * 24 + qd * 4;
                *(u32*)&EST[base]     = cvt_pk_bf16(Ev[ot][0], Ev[ot][1]);
                *(u32*)&EST[base + 2] = cvt_pk_bf16(Ev[ot][2], Ev[ot][3]);
            }
        }
        __syncthreads();   // P2-end

        // ---- P3: PV via MFMA + BD refill for pass ps+1.
        //      No trailing barrier: EST rewrite is in next P2, reachable only
        //      via next P1-end barrier; BD read in next P2 likewise. ----
        {
            float* dp2 = &BD[(ii * 16 + jj) * 4];
            dp2[0] = bdp0; dp2[1] = bdp1; dp2[2] = bdp2;
        }
#pragma unroll
        for (int hh = 0; hh < 8; ++hh) {
            const int h = wv * 8 + hh;
            bf16x8 af = (bf16x8){0, 0, 0, 0, 0, 0, 0, 0};
            if (qd < 2) af = *(const bf16x8*)&EST[h * 392 + ln * 24 + qd * 8];
#pragma unroll
            for (int nt = 0; nt < 2; ++nt) {
                bf16x8 bfr = (bf16x8){0, 0, 0, 0, 0, 0, 0, 0};
                if (qd < 2)
                    bfr = *(const bf16x8*)(cvT + ((size_t)(b * 1024 + h * 32 + nt * 16 + ln)) * 512 + jg0 + qd * 8);
                oacc[hh][nt] = MFMA_BF16(af, bfr, oacc[hh][nt], 0, 0, 0);
            }
        }
    }

    // ---- epilogue: write partials ----
    float* P = partial + (size_t)pidx * 18944;
#pragma unroll
    for (int hh = 0; hh < 8; ++hh)
#pragma unroll
        for (int nt = 0; nt < 2; ++nt)
#pragma unroll
            for (int r = 0; r < 4; ++r)
                P[(size_t)(qd * 4 + r) * 1024 + (wv * 8 + hh) * 32 + nt * 16 + ln] = oacc[hh][nt][r];
#pragma unroll
    for (int s = 0; s < 4; ++s)
#pragma unroll
        for (int ot = 0; ot < 4; ++ot) {
            float v = dn[s][ot];
            v += __shfl_xor(v, 16, 64);
            v += __shfl_xor(v, 32, 64);
            if (qd == 0) P[16384 + (wv * 4 + s) * 64 + ot * 16 + ln] = v;
        }
#pragma unroll
    for (int s = 0; s < 4; ++s)
#pragma unroll
        for (int d = 0; d < 3; ++d)
#pragma unroll
            for (int o = 0; o < 2; ++o) {
                float v = dd[s][d][o];
                v += __shfl_xor(v, 16, 64);
                v += __shfl_xor(v, 32, 64);
                if (qd == 0) P[17408 + (wv * 4 + s) * 96 + d * 32 + o * 16 + ln] = v;
            }
}

// ---------------------------------------------------------------------------
// finalize: per (b,it): combine 4 jq partials, normalize, Wo epilogue (MFMA),
// dis-MLP. 128 blocks x 256 threads.
// ---------------------------------------------------------------------------
__global__ __launch_bounds__(256, 2) void finalize(
    const float* __restrict__ partial, const u16* __restrict__ WoT,
    const float* __restrict__ bo,
    const float* __restrict__ Wd1, const float* __restrict__ bd1,
    const float* __restrict__ Wd2, const float* __restrict__ bd2,
    float* __restrict__ out0, float* __restrict__ out1)
{
    __shared__ float denomL[1024];
    __shared__ u16 preL[16 * 1032];
    __shared__ float odisL[1536];
    __shared__ float r1L[3072];

    const int tid = threadIdx.x;
    const int f = blockIdx.x;
    const int b = f >> 3, it = f & 7;
    const int row0 = b * 128 + it * 16;
    const float* P0 = partial + (size_t)(f * 4 + 0) * 18944;
    const float* P1 = partial + (size_t)(f * 4 + 1) * 18944;
    const float* P2 = partial + (size_t)(f * 4 + 2) * 18944;
    const float* P3 = partial + (size_t)(f * 4 + 3) * 18944;

    for (int k = tid; k < 1024; k += 256)
        denomL[k] = P0[16384 + k] + P1[16384 + k] + P2[16384 + k] + P3[16384 + k];
    __syncthreads();

    {
        const int h = tid >> 3;
#pragma unroll
        for (int i = 0; i < 16; ++i) {
            float4 a = *(const float4*)&P0[(size_t)i * 1024 + tid * 4];
            float4 bq = *(const float4*)&P1[(size_t)i * 1024 + tid * 4];
            float4 c = *(const float4*)&P2[(size_t)i * 1024 + tid * 4];
            float4 d = *(const float4*)&P3[(size_t)i * 1024 + tid * 4];
            float rdn = 1.f / denomL[i * 64 + h];
            u32 p0 = cvt_pk_bf16((a.x + bq.x + c.x + d.x) * rdn, (a.y + bq.y + c.y + d.y) * rdn);
            u32 p1 = cvt_pk_bf16((a.z + bq.z + c.z + d.z) * rdn, (a.w + bq.w + c.w + d.w) * rdn);
            *(uint2*)(void*)&preL[i * 1032 + tid * 4] = make_uint2(p0, p1);
        }
    }
    for (int idx = tid; idx < 1536; idx += 256) {
        int i = idx / 96, rm = idx % 96, h = rm & 31;
        odisL[idx] = (P0[17408 + idx] + P1[17408 + idx] + P2[17408 + idx] + P3[17408 + idx])
                     / denomL[i * 64 + 32 + h];
    }
    __syncthreads();

    {
        const int lane = tid & 63, wv = tid >> 6;
        const int qd = lane >> 4, ln = lane & 15;
        f32x4 acc[4];
#pragma unroll
        for (int nt = 0; nt < 4; ++nt) acc[nt] = (f32x4){0.f, 0.f, 0.f, 0.f};
#pragma clang loop unroll(disable)
        for (int ks = 0; ks < 32; ++ks) {
            bf16x8 af = *(const bf16x8*)&preL[ln * 1032 + ks * 32 + qd * 8];
#pragma unroll
            for (int nt = 0; nt < 4; ++nt) {
                bf16x8 wf = *(const bf16x8*)(WoT + ((size_t)(wv * 64 + nt * 16 + ln)) * 1024 + ks * 32 + qd * 8);
                acc[nt] = MFMA_BF16(af, wf, acc[nt], 0, 0, 0);
            }
        }
#pragma unroll
        for (int nt = 0; nt < 4; ++nt) {
            int col = wv * 64 + nt * 16 + ln;
            float bv = bo[col];
#pragma unroll
            for (int r = 0; r < 4; ++r)
                out0[(size_t)(row0 + qd * 4 + r) * 256 + col] = acc[nt][r] + bv;
        }
    }

    for (int idx = tid; idx < 3072; idx += 256) {
        int i = idx / 192, rm = idx % 192, d = rm / 64, c = rm & 63;
        float t = bd1[c];
#pragma unroll
        for (int hh = 0; hh < 32; ++hh)
            t += odisL[i * 96 + d * 32 + hh] * Wd1[hh * 64 + c];
        r1L[idx] = mishf(t);
    }
    __syncthreads();
    for (int idx = tid; idx < 1536; idx += 256) {
        int i = idx / 96, rm = idx % 96, d = rm >> 5, h = rm & 31;
        float v = bd2[h];
#pragma unroll
        for (int c = 0; c < 64; ++c)
            v += r1L[i * 192 + d * 64 + c] * Wd2[c * 32 + h];
        out1[(size_t)(row0 + i) * 96 + d * 32 + h] = v;
    }
}

extern "C" void kernel_launch(void* const* d_in, const int* in_sizes, int n_in,
                              void* d_out, int out_size, void* d_ws, size_t ws_size,
                              hipStream_t stream) {
    const float* x    = (const float*)d_in[0];
    const float* ctx  = (const float*)d_in[1];
    const float* bdis = (const float*)d_in[2];
    const float* bde  = (const float*)d_in[3];
    const float* Wqk  = (const float*)d_in[6];
    const float* Wcqk = (const float*)d_in[8];
    const float* Wcv  = (const float*)d_in[9];
    const float* Wm1  = (const float*)d_in[10];
    const float* Wm2  = (const float*)d_in[11];
    const float* bm2  = (const float*)d_in[12];
    const float* Wo   = (const float*)d_in[13];
    const float* bo   = (const float*)d_in[14];
    const float* Wd1  = (const float*)d_in[15];
    const float* bd1  = (const float*)d_in[16];
    const float* Wd2  = (const float*)d_in[17];
    const float* bd2  = (const float*)d_in[18];

    char* ws = (char*)d_ws;
    u16* qk_ws  = (u16*)(ws);                       // 4 MB
    u16* cqk_ws = (u16*)(ws + 4194304);             // 16 MB
    u16* cvT_ws = (u16*)(ws + 20971520);            // 16 MB
    u16* w1b    = (u16*)(ws + 37748736);            // 16 KB
    u16* w2b    = (u16*)(ws + 37765120);            // 16 KB
    u16* WoT    = (u16*)(ws + 37781504);            // 512 KB
    float* part = (float*)(ws + 38305792);          // 512*18944*4 = 38.8 MB

    float* out0 = (float*)d_out;
    float* out1 = out0 + (size_t)2048 * 256;

    const float SCALE = 0.17677669529663687f;       // 32^-0.5, folded into qk

    proj_fused<<<1409, 256, 0, stream>>>(x, Wqk, qk_ws, ctx, Wcqk, cqk_ws,
                                         Wcv, cvT_ws, Wo, Wm1, Wm2,
                                         WoT, w1b, w2b, SCALE);
    attn5<<<512, 256, 0, stream>>>(qk_ws, cqk_ws, cvT_ws, bde, bdis, w1b, w2b, bm2, part);
    finalize<<<128, 256, 0, stream>>>(part, WoT, bo, Wd1, bd1, Wd2, bd2, out0, out1);
}

// Round 9
// 473.120 us; speedup vs baseline: 1.2888x; 1.0704x over previous
//
#include <hip/hip_runtime.h>

typedef unsigned short u16;
typedef unsigned int   u32;
typedef __attribute__((ext_vector_type(8))) short bf16x8;
typedef __attribute__((ext_vector_type(4))) float f32x4;

#define MFMA_BF16 __builtin_amdgcn_mfma_f32_16x16x32_bf16
#define LOG2E 1.4426950408889634f

__device__ __forceinline__ u16 f2bf(float f) {
    u32 x = __builtin_bit_cast(u32, f);
    u32 r = (x + 0x7fffu + ((x >> 16) & 1u)) >> 16;
    return (u16)r;
}
// one-instruction pack: dst.lo = bf16(lo), dst.hi = bf16(hi)  (RNE)
__device__ __forceinline__ u32 cvt_pk_bf16(float lo, float hi) {
    u32 r;
    asm("v_cvt_pk_bf16_f32 %0, %1, %2" : "=v"(r) : "v"(lo), "v"(hi));
    return r;
}
__device__ __forceinline__ float exp2_asm(float x) {
    float r;
    asm("v_exp_f32 %0, %1" : "=v"(r) : "v"(x));
    return r;
}
__device__ __forceinline__ float rcp_asm(float x) {
    float r;
    asm("v_rcp_f32 %0, %1" : "=v"(r) : "v"(x));
    return r;
}
// mish(x) = x * (p^2-1)/(p^2+1), p = 1+e^x. Written as x*(1 - 2/(p^2+1)):
// graceful at both infinities (e=0 -> r=0; e=inf -> r=1), no cmp/sel, no div.
__device__ __forceinline__ float mishf(float x) {
    float e = exp2_asm(x * LOG2E);
    float p = 1.f + e;
    float d = __builtin_fmaf(p, p, 1.f);
    float r = __builtin_fmaf(-2.f, rcp_asm(d), 1.f);
    return x * r;
}

// ---------------------------------------------------------------------------
// proj_fused (unchanged from R8, verified): prep + 3 GEMMs + cv-transpose in
// ONE launch. Residue fell 273->206 us when this replaced 5 launches.
// ---------------------------------------------------------------------------
__global__ __launch_bounds__(256) void proj_fused(
    const float* __restrict__ x,   const float* __restrict__ Wqk,  u16* __restrict__ qk_ws,
    const float* __restrict__ ctx, const float* __restrict__ Wcqk, u16* __restrict__ cqk_ws,
    const float* __restrict__ Wcv, u16* __restrict__ cvT,
    const float* __restrict__ Wo,  const float* __restrict__ W1,   const float* __restrict__ W2,
    u16* __restrict__ WoT, u16* __restrict__ w1b, u16* __restrict__ w2b,
    float scale)
{
    __shared__ __align__(16) char smem[18432];
    const int id = blockIdx.x;
    const int tid = threadIdx.x;

    if (id >= 1152) {            // ---- prep branch ----
        const int bb = id - 1152, t = tid;
        if (bb < 256) {
#pragma unroll
            for (int kk = 0; kk < 4; ++kk)
                WoT[(size_t)t * 1024 + bb * 4 + kk] = f2bf(Wo[(size_t)(bb * 4 + kk) * 256 + t]);
        } else {
            for (int u = 0; u < 32; ++u) {        // W1: frag f = ks*8+nt
                int idx = t + 256 * u;
                int j = idx & 7, lane = (idx >> 3) & 63, f = idx >> 9;
                int n = lane & 15, q = lane >> 4, ntc = f & 7, ks = f >> 3;
                w1b[idx] = f2bf(W1[(ks * 32 + q * 8 + j) * 128 + ntc * 16 + n]);
            }
            for (int u = 0; u < 32; ++u) {        // W2: frag f = ks*4+ot, K-perm + log2e
                int idx = t + 256 * u;
                int j = idx & 7, lane = (idx >> 3) & 63, f = idx >> 9;
                int n = lane & 15, q = lane >> 4, ot = f & 3, ks = f >> 2;
                int k = q * 8 + j;
                int ch = ((k & 1) << 4) | (k >> 1);
                w2b[idx] = f2bf(W2[(ks * 32 + ch) * 64 + ot * 16 + n] * LOG2E);
            }
        }
        return;
    }

    // ---- GEMM branches: C[M,1024] = A[M,256] @ W[256,1024], 128x128 tile ----
    u16* As = (u16*)smem;                 // 10240 B
    u16* Bf = (u16*)(smem + 10240);       //  8192 B

    const float* A; const float* W; u16* C = qk_ws;
    int bx, by; bool cv = false; float sc = 1.0f;
    if (id < 128)      { A = x;   W = Wqk;  C = qk_ws;  bx = id & 7; by = id >> 3; sc = scale; }
    else if (id < 640) { A = ctx; W = Wcqk; C = cqk_ws; int i2 = id - 128; bx = i2 & 7; by = i2 >> 3; }
    else               { A = ctx; W = Wcv;              int i2 = id - 640; bx = i2 & 7; by = i2 >> 3; cv = true; }

    const int K = 256, N = 1024;
    const int lane = tid & 63, wv = tid >> 6;
    const int qd = lane >> 4, ln = lane & 15;
    const int m0 = by * 128, n0 = bx * 128;

    f32x4 acc[2][8];
#pragma unroll
    for (int a = 0; a < 2; ++a)
#pragma unroll
        for (int nt = 0; nt < 8; ++nt) acc[a][nt] = (f32x4){0.f, 0.f, 0.f, 0.f};

    for (int k0 = 0; k0 < K; k0 += 32) {
        {
            int r = tid >> 1, kh = (tid & 1) * 16;
            const float* ap = A + (size_t)(m0 + r) * K + k0 + kh;
            float4 a0 = ((const float4*)ap)[0];
            float4 a1 = ((const float4*)ap)[1];
            float4 a2 = ((const float4*)ap)[2];
            float4 a3 = ((const float4*)ap)[3];
            uint4 p0, p1;
            p0.x = cvt_pk_bf16(a0.x, a0.y);
            p0.y = cvt_pk_bf16(a0.z, a0.w);
            p0.z = cvt_pk_bf16(a1.x, a1.y);
            p0.w = cvt_pk_bf16(a1.z, a1.w);
            p1.x = cvt_pk_bf16(a2.x, a2.y);
            p1.y = cvt_pk_bf16(a2.z, a2.w);
            p1.z = cvt_pk_bf16(a3.x, a3.y);
            p1.w = cvt_pk_bf16(a3.z, a3.w);
            *(uint4*)&As[r * 40 + kh]     = p0;
            *(uint4*)&As[r * 40 + kh + 8] = p1;
        }
        {
            int ntA = tid >> 6, q = (tid >> 4) & 3, nn = tid & 15;
#pragma unroll
            for (int h = 0; h < 2; ++h) {
                int nt = ntA + h * 4;
                const float* wp = W + (size_t)(k0 + q * 8) * N + n0 + nt * 16 + nn;
                float w0 = wp[0], w1 = wp[(size_t)1 * N], w2 = wp[(size_t)2 * N], w3 = wp[(size_t)3 * N];
                float w4 = wp[(size_t)4 * N], w5 = wp[(size_t)5 * N], w6 = wp[(size_t)6 * N], w7 = wp[(size_t)7 * N];
                uint4 u;
                u.x = cvt_pk_bf16(w0, w1);
                u.y = cvt_pk_bf16(w2, w3);
                u.z = cvt_pk_bf16(w4, w5);
                u.w = cvt_pk_bf16(w6, w7);
                *(uint4*)&Bf[(nt * 64 + q * 16 + nn) * 8] = u;
            }
        }
        __syncthreads();
        bf16x8 af0 = *(const bf16x8*)&As[(wv * 32 + ln) * 40 + qd * 8];
        bf16x8 af1 = *(const bf16x8*)&As[(wv * 32 + 16 + ln) * 40 + qd * 8];
#pragma unroll
        for (int nt = 0; nt < 8; ++nt) {
            bf16x8 bfr = *(const bf16x8*)&Bf[(nt * 64 + lane) * 8];
            acc[0][nt] = MFMA_BF16(af0, bfr, acc[0][nt], 0, 0, 0);
            acc[1][nt] = MFMA_BF16(af1, bfr, acc[1][nt], 0, 0, 0);
        }
        __syncthreads();
    }

    if (!cv) {
#pragma unroll
        for (int a = 0; a < 2; ++a)
#pragma unroll
            for (int nt = 0; nt < 8; ++nt) {
                u32 pk0 = cvt_pk_bf16(acc[a][nt][0] * sc, acc[a][nt][1] * sc);
                u32 pk1 = cvt_pk_bf16(acc[a][nt][2] * sc, acc[a][nt][3] * sc);
                size_t base = (size_t)(m0 + wv * 32 + a * 16 + qd * 4) * N + n0 + nt * 16 + ln;
                C[base]               = (u16)pk0;
                C[base + (size_t)N]   = (u16)(pk0 >> 16);
                C[base + (size_t)2*N] = (u16)pk1;
                C[base + (size_t)3*N] = (u16)(pk1 >> 16);
            }
    } else {
        // ---- cv: transpose in LDS, write cvT[(b*1024+ch)*512 + j] directly ----
        const int b = m0 >> 9, jt = m0 & 511;
        u16* T = (u16*)smem;
#pragma unroll
        for (int h = 0; h < 2; ++h) {
            if (h) __syncthreads();   // h=0 safe: K-loop ended with a barrier
#pragma unroll
            for (int a = 0; a < 2; ++a)
#pragma unroll
                for (int t2 = 0; t2 < 4; ++t2) {
                    int nt = h * 4 + t2;
                    int chl = t2 * 16 + ln;
                    int row = wv * 32 + a * 16 + qd * 4;
                    uint2 pk;
                    pk.x = cvt_pk_bf16(acc[a][nt][0], acc[a][nt][1]);
                    pk.y = cvt_pk_bf16(acc[a][nt][2], acc[a][nt][3]);
                    *(uint2*)&T[chl * 136 + row] = pk;
                }
            __syncthreads();
            {
                int chl = tid >> 2, jseg = (tid & 3) * 32;
                const uint4* src = (const uint4*)&T[chl * 136 + jseg];
                u16* dst = cvT + ((size_t)(b * 1024 + n0 + h * 64 + chl)) * 512 + jt + jseg;
                ((uint4*)dst)[0] = src[0];
                ((uint4*)dst)[1] = src[1];
                ((uint4*)dst)[2] = src[2];
                ((uint4*)dst)[3] = src[3];
            }
        }
    }
}

// ---------------------------------------------------------------------------
// attn11: R7 structure + two work cuts (R9):
//  1. jq-MERGE: 256 blocks x 16 passes (was 512 x 8 in 2 serialized rounds).
//     One round, half the prologue/epilogue overhead, partial buffer halved
//     to 19.4 MB (finalize combines 2 partials, not 4).
//  2. cvT PREFETCH: P3's 16 B-frags loaded at P2-top (same mechanism as
//     R4's proven bde/cqk prefetch); post-P2 barrier vmcnt(0) guarantees
//     arrival, P2 body hides the latency. +64 VGPR transient (~372 of 512).
// R6 lesson standing: 1 wave/SIMD, register-rich.
// ---------------------------------------------------------------------------
__global__ __launch_bounds__(256, 1) void attn5(
    const u16* __restrict__ qk,      // [2048][1024] bf16 (scale folded)
    const u16* __restrict__ cqk,     // [8192][1024] bf16
    const u16* __restrict__ cvT,     // [16][1024][512] bf16
    const float* __restrict__ bde,   // [16][512][128][32]
    const float* __restrict__ bdis,  // [16][512][128][3]
    const u16* __restrict__ w1b, const u16* __restrict__ w2b,
    const float* __restrict__ b2,
    float* __restrict__ partial)
{
    __shared__ __align__(16) char smem[76288];
    u16*   ES  = (u16*)smem;             // 20480 B: [256 rows=(i*16+j)][40]
    u16*   MT  = (u16*)(smem + 20480);   // 10240 B: per-wave miniT, cg-dbuf
    float* BD  = (float*)(smem + 30720); //  4096 B: bdis stage [16 i][16 j][4]
    u16*   EST = (u16*)(smem + 34816);   // 25088 B: Estage [32 h][16 i][24+pad]
    u16*   W1B = (u16*)(smem + 59904);   // 16384 B: W1 frags (full size)

    const int tid = threadIdx.x;
    const int lane = tid & 63, wv = tid >> 6;
    const int qd = lane >> 4, ln = lane & 15;
    const int nblk = blockIdx.x;          // 256 blocks
    const int xcd = nblk & 7, g = nblk >> 3;
    const int b = xcd * 2 + (g & 1);
    const int r2 = g >> 1;                // 16: (it, jh)
    const int it = r2 >> 1, jh = r2 & 1;
    const int i0 = it * 16;
    const int jbase = jh * 256;
    const int pidx = (b * 8 + it) * 2 + jh;

    for (int k = tid; k < 4096; k += 256) ((u32*)W1B)[k] = ((const u32*)w1b)[k];

    float b2r[4];
#pragma unroll
    for (int ot = 0; ot < 4; ++ot) b2r[ot] = b2[ot * 16 + ln] * LOG2E;

    // qk A-frags: registers for the whole kernel (same i-tile every pass)
    bf16x8 qkf[8];
#pragma unroll
    for (int hh = 0; hh < 8; ++hh) {
        int h = wv * 8 + hh;
        qkf[hh] = *(const bf16x8*)(qk + ((size_t)(b * 128 + i0 + ln)) * 1024 + h * 32 + qd * 8);
    }

    const int ii = tid & 15, jj = tid >> 4;   // bdis stage mapping

    // ---- prologue: prefetch pass-0 inputs ----
    bf16x8 cqk_pf[8];
    float4 bde_pf[8];
    float bdp0, bdp1, bdp2;
    {
        const u16* crow = cqk + (size_t)(b * 512 + jbase + ln) * 1024 + qd * 8;
#pragma unroll
        for (int hh = 0; hh < 8; ++hh)
            cqk_pf[hh] = *(const bf16x8*)(crow + (wv * 8 + hh) * 32);
#pragma unroll
        for (int s2 = 0; s2 < 4; ++s2) {
            const float* dps = bde + (((size_t)(b * 512 + jbase + ln)) * 128 + i0 + wv * 4 + s2) * 32 + qd * 8;
            bde_pf[s2 * 2]     = ((const float4*)dps)[0];
            bde_pf[s2 * 2 + 1] = ((const float4*)dps)[1];
        }
        const float* sp = bdis + ((size_t)(b * 512 + jbase + jj) * 128 + i0 + ii) * 3;
        bdp0 = sp[0]; bdp1 = sp[1]; bdp2 = sp[2];
        float* dp2 = &BD[(ii * 16 + jj) * 4];
        dp2[0] = bdp0; dp2[1] = bdp1; dp2[2] = bdp2;
    }

    f32x4 oacc[8][2];
#pragma unroll
    for (int a = 0; a < 8; ++a)
#pragma unroll
        for (int c = 0; c < 2; ++c) oacc[a][c] = (f32x4){0.f, 0.f, 0.f, 0.f};
    float dn[4][4] = {};
    float dd[4][3][2] = {};

    __syncthreads();   // W1B + BD(pass0) visible; prologue prefetch drained

#pragma clang loop unroll(disable)
    for (int ps = 0; ps < 16; ++ps) {
        const int jg0 = jbase + ps * 16;

        // ---- P1: sim (MFMA) -> ES (pure compute: operands in registers) ----
        {
            bf16x8 cqk_use[8];
#pragma unroll
            for (int hh = 0; hh < 8; ++hh) cqk_use[hh] = cqk_pf[hh];
#pragma unroll
            for (int hh = 0; hh < 4; ++hh) {
                const int h0 = wv * 8 + hh * 2;
                f32x4 c0 = (f32x4){0.f, 0.f, 0.f, 0.f}, c1 = c0;
                c0 = MFMA_BF16(qkf[hh * 2],     cqk_use[hh * 2],     c0, 0, 0, 0);
                c1 = MFMA_BF16(qkf[hh * 2 + 1], cqk_use[hh * 2 + 1], c1, 0, 0, 0);
#pragma unroll
                for (int r = 0; r < 4; ++r)
                    *(u32*)&ES[((qd * 4 + r) * 16 + ln) * 40 + h0] = cvt_pk_bf16(c0[r], c1[r]);
            }
        }
        __syncthreads();   // P1-end

        // ---- P2 top: prefetch pass ps+1 (bde/cqk/bdis) AND this pass's
        //      cvT B-frags for P3 (arrival forced by post-P2 vmcnt(0)) ----
        const int psn = (ps < 15) ? ps + 1 : 15;   // clamp: avoid OOB prefetch
        const int jgn = jbase + psn * 16;
        float4 bde_use[8];
#pragma unroll
        for (int k = 0; k < 8; ++k) bde_use[k] = bde_pf[k];
        bf16x8 cvt_pf[16];
        {
            const u16* crow = cqk + (size_t)(b * 512 + jgn + ln) * 1024 + qd * 8;
#pragma unroll
            for (int hh = 0; hh < 8; ++hh)
                cqk_pf[hh] = *(const bf16x8*)(crow + (wv * 8 + hh) * 32);
#pragma unroll
            for (int s2 = 0; s2 < 4; ++s2) {
                const float* dps = bde + (((size_t)(b * 512 + jgn + ln)) * 128 + i0 + wv * 4 + s2) * 32 + qd * 8;
                bde_pf[s2 * 2]     = ((const float4*)dps)[0];
                bde_pf[s2 * 2 + 1] = ((const float4*)dps)[1];
            }
            const float* sp = bdis + ((size_t)(b * 512 + jgn + jj) * 128 + i0 + ii) * 3;
            bdp0 = sp[0]; bdp1 = sp[1]; bdp2 = sp[2];
#pragma unroll
            for (int hh = 0; hh < 8; ++hh) {
                const int h = wv * 8 + hh;
#pragma unroll
                for (int nt = 0; nt < 2; ++nt) {
                    cvt_pf[hh * 2 + nt] = (bf16x8){0, 0, 0, 0, 0, 0, 0, 0};
                    if (qd < 2)
                        cvt_pf[hh * 2 + nt] = *(const bf16x8*)(cvT +
                            ((size_t)(b * 1024 + h * 32 + nt * 16 + ln)) * 512 + jg0 + qd * 8);
                }
            }
        }

        // ---- P2: per s (i = wv*4+s): MLP1 -> mish -> MLP2 -> exp2 -> Estage ----
#pragma unroll
        for (int s = 0; s < 4; ++s) {
            const int i_loc = wv * 4 + s;
            bf16x8 af0 = *(const bf16x8*)&ES[(i_loc * 16 + ln) * 40 + qd * 8];
            bf16x8 af1;
            {
                float4 a0 = bde_use[s * 2];
                float4 a1 = bde_use[s * 2 + 1];
                uint4 u;
                u.x = cvt_pk_bf16(a0.x, a0.y);
                u.y = cvt_pk_bf16(a0.z, a0.w);
                u.z = cvt_pk_bf16(a1.x, a1.y);
                u.w = cvt_pk_bf16(a1.z, a1.w);
                af1 = __builtin_bit_cast(bf16x8, u);
            }
            f32x4 uacc[4];
#pragma unroll
            for (int ot = 0; ot < 4; ++ot) uacc[ot] = (f32x4){0.f, 0.f, 0.f, 0.f};
#pragma unroll
            for (int cg = 0; cg < 4; ++cg) {
                u16* mtp = MT + wv * 1280 + (cg & 1) * 640;   // cg-parity dbuf
                bf16x8 w00 = *(const bf16x8*)&W1B[((cg * 2 + 0) * 64 + lane) * 8];
                bf16x8 w01 = *(const bf16x8*)&W1B[((cg * 2 + 1) * 64 + lane) * 8];
                bf16x8 w10 = *(const bf16x8*)&W1B[((8 + cg * 2 + 0) * 64 + lane) * 8];
                bf16x8 w11 = *(const bf16x8*)&W1B[((8 + cg * 2 + 1) * 64 + lane) * 8];
                f32x4 t0 = (f32x4){0.f, 0.f, 0.f, 0.f}, t1 = t0;
                t0 = MFMA_BF16(af0, w00, t0, 0, 0, 0);
                t0 = MFMA_BF16(af1, w10, t0, 0, 0, 0);
                t1 = MFMA_BF16(af0, w01, t1, 0, 0, 0);
                t1 = MFMA_BF16(af1, w11, t1, 0, 0, 0);
                // packed mish pair -> one ds_write_b32; u16 slot 2m holds ch m,
                // slot 2m+1 holds ch 16+m (w2b K-order permuted to match)
#pragma unroll
                for (int r = 0; r < 4; ++r) {
                    u32 pk = cvt_pk_bf16(mishf(t0[r]), mishf(t1[r]));
                    *(u32*)&mtp[(qd * 4 + r) * 40 + (ln << 1)] = pk;
                }
                bf16x8 ta = *(const bf16x8*)&mtp[ln * 40 + qd * 8];
#pragma unroll
                for (int ot = 0; ot < 4; ++ot) {
                    bf16x8 wf = *(const bf16x8*)(w2b + ((size_t)(cg * 4 + ot) * 64 + lane) * 8);
                    uacc[ot] = MFMA_BF16(ta, wf, uacc[ot], 0, 0, 0);
                }
            }
            float Ev[4][4];
#pragma unroll
            for (int ot = 0; ot < 4; ++ot) {
#pragma unroll
                for (int r = 0; r < 4; ++r) Ev[ot][r] = exp2_asm(uacc[ot][r] + b2r[ot]);
                dn[s][ot] += (Ev[ot][0] + Ev[ot][1]) + (Ev[ot][2] + Ev[ot][3]);
            }
#pragma unroll
            for (int r = 0; r < 4; ++r) {
                float4 bp = *(const float4*)&BD[(i_loc * 16 + qd * 4 + r) * 4];
                dd[s][0][0] += Ev[2][r] * bp.x; dd[s][0][1] += Ev[3][r] * bp.x;
                dd[s][1][0] += Ev[2][r] * bp.y; dd[s][1][1] += Ev[3][r] * bp.y;
                dd[s][2][0] += Ev[2][r] * bp.z; dd[s][2][1] += Ev[3][r] * bp.z;
            }
#pragma unroll
            for (int ot = 0; ot < 2; ++ot) {
                const int base = (ot * 16 + ln) * 392 + i_loc * 24 + qd * 4;
                *(u32*)&EST[base]     = cvt_pk_bf16(Ev[ot][0], Ev[ot][1]);
                *(u32*)&EST[base + 2] = cvt_pk_bf16(Ev[ot][2], Ev[ot][3]);
            }
        }
        __syncthreads();   // P2-end (drains all prefetch loads incl. cvT)

        // ---- P3: PV via MFMA (B-frags prefetched) + BD refill for ps+1.
        //      No trailing barrier: EST rewrite is in next P2, reachable only
        //      via next P1-end barrier; BD read in next P2 likewise. ----
        {
            float* dp2 = &BD[(ii * 16 + jj) * 4];
            dp2[0] = bdp0; dp2[1] = bdp1; dp2[2] = bdp2;
        }
#pragma unroll
        for (int hh = 0; hh < 8; ++hh) {
            const int h = wv * 8 + hh;
            bf16x8 af = (bf16x8){0, 0, 0, 0, 0, 0, 0, 0};
            if (qd < 2) af = *(const bf16x8*)&EST[h * 392 + ln * 24 + qd * 8];
#pragma unroll
            for (int nt = 0; nt < 2; ++nt)
                oacc[hh][nt] = MFMA_BF16(af, cvt_pf[hh * 2 + nt], oacc[hh][nt], 0, 0, 0);
        }
    }

    // ---- epilogue: write partials ----
    float* P = partial + (size_t)pidx * 18944;
#pragma unroll
    for (int hh = 0; hh < 8; ++hh)
#pragma unroll
        for (int nt = 0; nt < 2; ++nt)
#pragma unroll
            for (int r = 0; r < 4; ++r)
                P[(size_t)(qd * 4 + r) * 1024 + (wv * 8 + hh) * 32 + nt * 16 + ln] = oacc[hh][nt][r];
#pragma unroll
    for (int s = 0; s < 4; ++s)
#pragma unroll
        for (int ot = 0; ot < 4; ++ot) {
            float v = dn[s][ot];
            v += __shfl_xor(v, 16, 64);
            v += __shfl_xor(v, 32, 64);
            if (qd == 0) P[16384 + (wv * 4 + s) * 64 + ot * 16 + ln] = v;
        }
#pragma unroll
    for (int s = 0; s < 4; ++s)
#pragma unroll
        for (int d = 0; d < 3; ++d)
#pragma unroll
            for (int o = 0; o < 2; ++o) {
                float v = dd[s][d][o];
                v += __shfl_xor(v, 16, 64);
                v += __shfl_xor(v, 32, 64);
                if (qd == 0) P[17408 + (wv * 4 + s) * 96 + d * 32 + o * 16 + ln] = v;
            }
}

// ---------------------------------------------------------------------------
// finalize: per (b,it): combine 2 jh partials (R9: was 4 jq), normalize,
// Wo epilogue (MFMA), dis-MLP. 128 blocks x 256 threads.
// ---------------------------------------------------------------------------
__global__ __launch_bounds__(256, 2) void finalize(
    const float* __restrict__ partial, const u16* __restrict__ WoT,
    const float* __restrict__ bo,
    const float* __restrict__ Wd1, const float* __restrict__ bd1,
    const float* __restrict__ Wd2, const float* __restrict__ bd2,
    float* __restrict__ out0, float* __restrict__ out1)
{
    __shared__ float denomL[1024];
    __shared__ u16 preL[16 * 1032];
    __shared__ float odisL[1536];
    __shared__ float r1L[3072];

    const int tid = threadIdx.x;
    const int f = blockIdx.x;
    const int b = f >> 3, it = f & 7;
    const int row0 = b * 128 + it * 16;
    const float* P0 = partial + (size_t)(f * 2 + 0) * 18944;
    const float* P1 = partial + (size_t)(f * 2 + 1) * 18944;

    for (int k = tid; k < 1024; k += 256)
        denomL[k] = P0[16384 + k] + P1[16384 + k];
    __syncthreads();

    {
        const int h = tid >> 3;
#pragma unroll
        for (int i = 0; i < 16; ++i) {
            float4 a = *(const float4*)&P0[(size_t)i * 1024 + tid * 4];
            float4 bq = *(const float4*)&P1[(size_t)i * 1024 + tid * 4];
            float rdn = 1.f / denomL[i * 64 + h];
            u32 p0 = cvt_pk_bf16((a.x + bq.x) * rdn, (a.y + bq.y) * rdn);
            u32 p1 = cvt_pk_bf16((a.z + bq.z) * rdn, (a.w + bq.w) * rdn);
            *(uint2*)(void*)&preL[i * 1032 + tid * 4] = make_uint2(p0, p1);
        }
    }
    for (int idx = tid; idx < 1536; idx += 256) {
        int i = idx / 96, rm = idx % 96, h = rm & 31;
        odisL[idx] = (P0[17408 + idx] + P1[17408 + idx])
                     / denomL[i * 64 + 32 + h];
    }
    __syncthreads();

    {
        const int lane = tid & 63, wv = tid >> 6;
        const int qd = lane >> 4, ln = lane & 15;
        f32x4 acc[4];
#pragma unroll
        for (int nt = 0; nt < 4; ++nt) acc[nt] = (f32x4){0.f, 0.f, 0.f, 0.f};
#pragma clang loop unroll(disable)
        for (int ks = 0; ks < 32; ++ks) {
            bf16x8 af = *(const bf16x8*)&preL[ln * 1032 + ks * 32 + qd * 8];
#pragma unroll
            for (int nt = 0; nt < 4; ++nt) {
                bf16x8 wf = *(const bf16x8*)(WoT + ((size_t)(wv * 64 + nt * 16 + ln)) * 1024 + ks * 32 + qd * 8);
                acc[nt] = MFMA_BF16(af, wf, acc[nt], 0, 0, 0);
            }
        }
#pragma unroll
        for (int nt = 0; nt < 4; ++nt) {
            int col = wv * 64 + nt * 16 + ln;
            float bv = bo[col];
#pragma unroll
            for (int r = 0; r < 4; ++r)
                out0[(size_t)(row0 + qd * 4 + r) * 256 + col] = acc[nt][r] + bv;
        }
    }

    for (int idx = tid; idx < 3072; idx += 256) {
        int i = idx / 192, rm = idx % 192, d = rm / 64, c = rm & 63;
        float t = bd1[c];
#pragma unroll
        for (int hh = 0; hh < 32; ++hh)
            t += odisL[i * 96 + d * 32 + hh] * Wd1[hh * 64 + c];
        r1L[idx] = mishf(t);
    }
    __syncthreads();
    for (int idx = tid; idx < 1536; idx += 256) {
        int i = idx / 96, rm = idx % 96, d = rm >> 5, h = rm & 31;
        float v = bd2[h];
#pragma unroll
        for (int c = 0; c < 64; ++c)
            v += r1L[i * 192 + d * 64 + c] * Wd2[c * 32 + h];
        out1[(size_t)(row0 + i) * 96 + d * 32 + h] = v;
    }
}

extern "C" void kernel_launch(void* const* d_in, const int* in_sizes, int n_in,
                              void* d_out, int out_size, void* d_ws, size_t ws_size,
                              hipStream_t stream) {
    const float* x    = (const float*)d_in[0];
    const float* ctx  = (const float*)d_in[1];
    const float* bdis = (const float*)d_in[2];
    const float* bde  = (const float*)d_in[3];
    const float* Wqk  = (const float*)d_in[6];
    const float* Wcqk = (const float*)d_in[8];
    const float* Wcv  = (const float*)d_in[9];
    const float* Wm1  = (const float*)d_in[10];
    const float* Wm2  = (const float*)d_in[11];
    const float* bm2  = (const float*)d_in[12];
    const float* Wo   = (const float*)d_in[13];
    const float* bo   = (const float*)d_in[14];
    const float* Wd1  = (const float*)d_in[15];
    const float* bd1  = (const float*)d_in[16];
    const float* Wd2  = (const float*)d_in[17];
    const float* bd2  = (const float*)d_in[18];

    char* ws = (char*)d_ws;
    u16* qk_ws  = (u16*)(ws);                       // 4 MB
    u16* cqk_ws = (u16*)(ws + 4194304);             // 16 MB
    u16* cvT_ws = (u16*)(ws + 20971520);            // 16 MB
    u16* w1b    = (u16*)(ws + 37748736);            // 16 KB
    u16* w2b    = (u16*)(ws + 37765120);            // 16 KB
    u16* WoT    = (u16*)(ws + 37781504);            // 512 KB
    float* part = (float*)(ws + 38305792);          // 256*18944*4 = 19.4 MB

    float* out0 = (float*)d_out;
    float* out1 = out0 + (size_t)2048 * 256;

    const float SCALE = 0.17677669529663687f;       // 32^-0.5, folded into qk

    proj_fused<<<1409, 256, 0, stream>>>(x, Wqk, qk_ws, ctx, Wcqk, cqk_ws,
                                         Wcv, cvT_ws, Wo, Wm1, Wm2,
                                         WoT, w1b, w2b, SCALE);
    attn5<<<256, 256, 0, stream>>>(qk_ws, cqk_ws, cvT_ws, bde, bdis, w1b, w2b, bm2, part);
    finalize<<<128, 256, 0, stream>>>(part, WoT, bo, Wd1, bd1, Wd2, bd2, out0, out1);
}